// Round 8
// baseline (197.318 us; speedup 1.0000x reference)
//
#include <hip/hip_runtime.h>
#include <hip/hip_bf16.h>

#define N_NODES 50000
#define N_EDGES 800000
#define N_FEAT 512
#define HIDDEN 128
#define N_CLASSES 32

#define NBUCK 196        // coarse buckets: src>>8 (256-node regions)
#define REG_STRIDE 6144  // slots per region (mean 4081, sigma 64 -> 30+ sigma headroom)

typedef __attribute__((ext_vector_type(8))) short bf16x8;
typedef __attribute__((ext_vector_type(4))) float f32x4;

// round-to-nearest-even f32 -> bf16 bits
static __device__ __forceinline__ unsigned short f2bf(float f) {
    unsigned u = __float_as_uint(f);
    u += 0x7FFFu + ((u >> 16) & 1u);
    return (unsigned short)(u >> 16);
}
// unpack uint = (bf16_hi<<16)|bf16_lo
static __device__ __forceinline__ float bflo(unsigned u) { return __uint_as_float(u << 16); }
static __device__ __forceinline__ float bfhi(unsigned u) { return __uint_as_float(u & 0xFFFF0000u); }
static __device__ __forceinline__ unsigned pack2(float a, float b) {
    return (unsigned)f2bf(a) | ((unsigned)f2bf(b) << 16);
}

// ---------------- CSR build, phase 1: LDS-bucketed coarse scatter ----------------
// record: src(16) | dst(16)<<16 | val_bits<<32

__global__ __launch_bounds__(256) void bucket1_k(const int* __restrict__ src, const int* __restrict__ dst,
                                                 const float* __restrict__ val,
                                                 int* __restrict__ gcursor,
                                                 unsigned long long* __restrict__ tmp) {
    __shared__ int cnt[256];
    __shared__ int lstart[256];
    __shared__ int lcur[256];
    __shared__ int gbase[256];
    __shared__ unsigned long long buf[2048];   // 16 KB
    const int t = threadIdx.x;
    const int e0 = blockIdx.x * 2048;
    const int ne = min(2048, N_EDGES - e0);

    cnt[t] = 0;
    __syncthreads();

    unsigned long long rec[8];
    int rb[8];
#pragma unroll
    for (int j = 0; j < 8; ++j) {
        int p = j * 256 + t;
        rec[j] = 0; rb[j] = -1;
        if (p < ne) {
            int i = e0 + p;
            unsigned s = (unsigned)src[i];
            rec[j] = (unsigned long long)(s | ((unsigned)dst[i] << 16))
                   | ((unsigned long long)__float_as_uint(val[i]) << 32);
            int b = (int)(s >> 8);
            rb[j] = b;
            atomicAdd(&cnt[b], 1);
        }
    }
    __syncthreads();
    const int cv = cnt[t];
    // inclusive scan (Hillis-Steele)
    for (int off = 1; off < 256; off <<= 1) {
        int xv = (t >= off) ? cnt[t - off] : 0;
        __syncthreads();
        cnt[t] += xv;
        __syncthreads();
    }
    lstart[t] = cnt[t] - cv;
    lcur[t]   = cnt[t] - cv;
    if (t < NBUCK) gbase[t] = atomicAdd(&gcursor[t], cv);
    __syncthreads();
    // place records bucket-grouped into LDS
#pragma unroll
    for (int j = 0; j < 8; ++j) {
        if (rb[j] >= 0) {
            int pos = atomicAdd(&lcur[rb[j]], 1);
            buf[pos] = rec[j];
        }
    }
    __syncthreads();
    // burst write-out: consecutive p within a bucket -> consecutive global slots
#pragma unroll
    for (int j = 0; j < 8; ++j) {
        int p = j * 256 + t;
        if (p < ne) {
            unsigned long long r = buf[p];
            int b = (int)((r & 0xFFFFu) >> 8);
            int tgt = gbase[b] + (p - lstart[b]);
            tmp[(size_t)b * REG_STRIDE + tgt] = r;
        }
    }
}

// ---------------- CSR build, phase 2: per-region local sort + row_ptr ----------------

__global__ __launch_bounds__(256) void bucket2_k(const int* __restrict__ gcursor,
                                                 const unsigned long long* __restrict__ tmp,
                                                 unsigned long long* __restrict__ csr_ev,
                                                 int* __restrict__ row_ptr) {
    __shared__ int lcnt[256];
    __shared__ int lcur[256];
    __shared__ int cnts[NBUCK];
    __shared__ int base_s;
    const int b = blockIdx.x;
    const int t = threadIdx.x;
    if (t < NBUCK) cnts[t] = gcursor[t];
    lcnt[t] = 0;
    __syncthreads();
    const int nb = cnts[b];
    if (t == 0) {
        int s = 0;
        for (int r = 0; r < b; ++r) s += cnts[r];
        base_s = s;
    }
    const unsigned long long* reg = tmp + (size_t)b * REG_STRIDE;
    __syncthreads();
    // pass 1: per-node counts (local node = rec & 255, regions are 256-aligned)
    for (int p = t; p < nb; p += 256)
        atomicAdd(&lcnt[(int)(reg[p] & 0xFFu)], 1);
    __syncthreads();
    const int cv = lcnt[t];
    for (int off = 1; off < 256; off <<= 1) {
        int xv = (t >= off) ? lcnt[t - off] : 0;
        __syncthreads();
        lcnt[t] += xv;
        __syncthreads();
    }
    const int abs_start = base_s + lcnt[t] - cv;
    lcur[t] = abs_start;
    int node = b * 256 + t;
    if (node <= N_NODES) row_ptr[node] = abs_start;
    __syncthreads();
    // pass 2: place (L2-hot ~33KB window)
    for (int p = t; p < nb; p += 256) {
        unsigned long long r = reg[p];
        int pos = atomicAdd(&lcur[(int)(r & 0xFFu)], 1);
        csr_ev[pos] = ((r >> 16) & 0xFFFFull) | (r & 0xFFFFFFFF00000000ull);
    }
}

// ---------------- W1 transpose + bf16 (+ gcursor zero): W1[512][128] -> W1t[128][512] ----------------

__global__ __launch_bounds__(256) void w1conv_k(const float* __restrict__ W1,
                                                unsigned short* __restrict__ W1t,
                                                int* __restrict__ gcursor) {
    if (blockIdx.x == 0 && threadIdx.x < NBUCK) gcursor[threadIdx.x] = 0;
    int id = blockIdx.x * 256 + threadIdx.x;   // 65536
    int c = id >> 9;          // 0..127
    int k = id & 511;         // 0..511
    W1t[(size_t)c * N_FEAT + k] = f2bf(W1[(size_t)k * HIDDEN + c]);
}

// ---------------- GEMM1 via bf16 MFMA, barrier-free streaming ----------------
// One wave per 16 output rows (3125 waves). No LDS, no __syncthreads.
// A-frag: lane reads its own x row (2 x float4 per K-step), cvt to bf16 in reg.
// B-frag: direct 16B load from W1t[col][k] (L2/L1-hot 128 KB), exact MFMA layout.
// Per wave: 16 K-steps x { 2 A-loads, 8 B-loads, 8 MFMA }.

__global__ __launch_bounds__(256, 4) void gemm1_mfma(const float* __restrict__ x,
                                                     const unsigned short* __restrict__ W1t,
                                                     unsigned short* __restrict__ pre1b) {
    const int t = threadIdx.x;
    const int w = t >> 6;
    const int l = t & 63;
    const int wid = blockIdx.x * 4 + w;        // wave id = 16-row group
    if (wid >= N_NODES / 16) return;           // 3125 groups exactly
    const int l15 = l & 15;
    const int lhi = l >> 4;

    const float* xr = x + (size_t)(wid * 16 + l15) * N_FEAT + lhi * 8;

    f32x4 acc[8];
#pragma unroll
    for (int n = 0; n < 8; ++n) acc[n] = (f32x4){0.f, 0.f, 0.f, 0.f};

#pragma unroll 2
    for (int k0 = 0; k0 < N_FEAT; k0 += 32) {
        float4 a0 = *(const float4*)(xr + k0);
        float4 a1 = *(const float4*)(xr + k0 + 4);
        ushort4 h0, h1;
        h0.x = f2bf(a0.x); h0.y = f2bf(a0.y); h0.z = f2bf(a0.z); h0.w = f2bf(a0.w);
        h1.x = f2bf(a1.x); h1.y = f2bf(a1.y); h1.z = f2bf(a1.z); h1.w = f2bf(a1.w);
        bf16x8 af;
        af[0] = (short)h0.x; af[1] = (short)h0.y; af[2] = (short)h0.z; af[3] = (short)h0.w;
        af[4] = (short)h1.x; af[5] = (short)h1.y; af[6] = (short)h1.z; af[7] = (short)h1.w;
        const unsigned short* bp = W1t + (size_t)l15 * N_FEAT + k0 + lhi * 8;
#pragma unroll
        for (int n = 0; n < 8; ++n) {
            bf16x8 bf = *(const bf16x8*)(bp + (size_t)(n * 16) * N_FEAT);
            acc[n] = __builtin_amdgcn_mfma_f32_16x16x32_bf16(af, bf, acc[n], 0, 0, 0);
        }
    }
    // epilogue: C/D layout col=lane&15, row=(lane>>4)*4+reg ; rows all valid (50000=3125*16)
    unsigned short* orow = pre1b + (size_t)(wid * 16 + lhi * 4) * HIDDEN + l15;
#pragma unroll
    for (int n = 0; n < 8; ++n)
#pragma unroll
        for (int j = 0; j < 4; ++j)
            orow[(size_t)j * HIDDEN + n * 16] = f2bf(acc[n][j]);
}

// ---------------- SpMM1: hb = bf16(relu(A @ pre1)), one wave per node, 1 uint (2 feats)/lane ----------------

__global__ __launch_bounds__(256) void spmm1_k(const int* __restrict__ rp,
                                               const unsigned long long* __restrict__ ce,
                                               const unsigned* __restrict__ P,
                                               unsigned* __restrict__ hb) {
    const int g = threadIdx.x >> 6;
    const int lane = threadIdx.x & 63;
    const int node = blockIdx.x * 4 + g;
    if (node >= N_NODES) return;
    const int s = rp[node], e = rp[node + 1];
    float2 a0; a0.x = 0.f; a0.y = 0.f;
    float2 a1; a1.x = 0.f; a1.y = 0.f;
    int i = s;
    for (; i + 2 <= e; i += 2) {
        unsigned long long e0 = ce[i], e1 = ce[i + 1];
        int d0 = (int)(unsigned)e0, d1 = (int)(unsigned)e1;
        float v0 = __uint_as_float((unsigned)(e0 >> 32));
        float v1 = __uint_as_float((unsigned)(e1 >> 32));
        unsigned u0 = P[(size_t)d0 * 64 + lane];
        unsigned u1 = P[(size_t)d1 * 64 + lane];
        a0.x += v0 * bflo(u0); a0.y += v0 * bfhi(u0);
        a1.x += v1 * bflo(u1); a1.y += v1 * bfhi(u1);
    }
    if (i < e) {
        unsigned long long e0 = ce[i];
        int d0 = (int)(unsigned)e0;
        float v0 = __uint_as_float((unsigned)(e0 >> 32));
        unsigned u0 = P[(size_t)d0 * 64 + lane];
        a0.x += v0 * bflo(u0); a0.y += v0 * bfhi(u0);
    }
    a0.x += a1.x; a0.y += a1.y;
    a0.x = a0.x > 0.f ? a0.x : 0.f;
    a0.y = a0.y > 0.f ? a0.y : 0.f;
    hb[(size_t)node * 64 + lane] = pack2(a0.x, a0.y);
}

// ---------------- GEMM2: pre2b[50000,32] = bf16(h @ W2) ----------------

__global__ __launch_bounds__(256) void gemm2_k(const unsigned* __restrict__ hb,
                                               const float* __restrict__ W2,
                                               unsigned short* __restrict__ pre2b) {
    __shared__ float hs[32][132];
    __shared__ float w2s[HIDDEN][N_CLASSES];
    const int t = threadIdx.x;
    const int row0 = blockIdx.x * 32;
#pragma unroll
    for (int j = 0; j < 4; ++j) {        // W2: 1024 float4
        int f = j * 256 + t;
        int r = f >> 3;
        int c = (f & 7) << 2;
        *(float4*)&w2s[r][c] = *(const float4*)(W2 + (size_t)r * N_CLASSES + c);
    }
#pragma unroll
    for (int j = 0; j < 2; ++j) {        // h tile: 32 rows x 64 uints = 2048 uints
        int f = j * 256 + t;
        int r = f >> 4;                  // 0..31
        int cu = (f & 15) << 2;          // uint col 0..60 step 4
        int grr = row0 + r;
        if (grr >= N_NODES) grr = N_NODES - 1;
        uint4 u = *(const uint4*)(hb + (size_t)grr * 64 + cu);
        hs[r][2 * cu + 0] = bflo(u.x); hs[r][2 * cu + 1] = bfhi(u.x);
        hs[r][2 * cu + 2] = bflo(u.y); hs[r][2 * cu + 3] = bfhi(u.y);
        hs[r][2 * cu + 4] = bflo(u.z); hs[r][2 * cu + 5] = bfhi(u.z);
        hs[r][2 * cu + 6] = bflo(u.w); hs[r][2 * cu + 7] = bfhi(u.w);
    }
    __syncthreads();
    const int r = t >> 3;
    const int c = (t & 7) << 2;
    float4 acc; acc.x = acc.y = acc.z = acc.w = 0.f;
#pragma unroll 16
    for (int kk = 0; kk < HIDDEN; ++kk) {
        float a = hs[r][kk];
        float4 b = *(const float4*)&w2s[kk][c];
        acc.x += a * b.x; acc.y += a * b.y; acc.z += a * b.z; acc.w += a * b.w;
    }
    int grr = row0 + r;
    if (grr < N_NODES) {
        uint2 o;
        o.x = pack2(acc.x, acc.y);
        o.y = pack2(acc.z, acc.w);
        *(uint2*)&pre2b[(size_t)grr * N_CLASSES + c] = o;
    }
}

// ---------------- SpMM2: out = A @ pre2 ; 16 lanes/edge, 4 edges/iter ----------------

__global__ __launch_bounds__(256) void spmm2_k(const int* __restrict__ rp,
                                               const unsigned long long* __restrict__ ce,
                                               const unsigned* __restrict__ P2,
                                               float* __restrict__ out) {
    const int g = threadIdx.x >> 6;
    const int lane = threadIdx.x & 63;
    const int node = blockIdx.x * 4 + g;
    if (node >= N_NODES) return;
    const int s = rp[node], e = rp[node + 1];
    const int f2 = lane & 15;      // uint index: feats 2*f2, 2*f2+1
    const int par = lane >> 4;     // 0..3
    float ax = 0.f, ay = 0.f;
    for (int i = s + par; i < e; i += 4) {
        unsigned long long ed = ce[i];
        int dst = (int)(unsigned)ed;
        float v = __uint_as_float((unsigned)(ed >> 32));
        unsigned u = P2[(size_t)dst * 16 + f2];
        ax += v * bflo(u);
        ay += v * bfhi(u);
    }
    ax += __shfl_xor(ax, 16); ay += __shfl_xor(ay, 16);
    ax += __shfl_xor(ax, 32); ay += __shfl_xor(ay, 32);
    if (lane < 16) {
        float2 o; o.x = ax; o.y = ay;
        ((float2*)out)[(size_t)node * 16 + f2] = o;
    }
}

// ---------------- launch ----------------

extern "C" void kernel_launch(void* const* d_in, const int* in_sizes, int n_in,
                              void* d_out, int out_size, void* d_ws, size_t ws_size,
                              hipStream_t stream) {
    const float* x    = (const float*)d_in[0];
    const int* esrc   = (const int*)d_in[1];
    const int* edst   = (const int*)d_in[2];
    const float* ev   = (const float*)d_in[3];
    const float* W1   = (const float*)d_in[4];
    const float* W2   = (const float*)d_in[5];
    float* out        = (float*)d_out;

    // workspace layout; pre2b aliases pre1b (pre1b dead after spmm1)
    unsigned short* pre1b = (unsigned short*)d_ws;            // 6,400,000 ushort (12.8 MB)
    unsigned* hb          = (unsigned*)(pre1b + 6400000);     // 3,200,000 uint (12.8 MB)
    unsigned short* pre2b = pre1b;                            // alias
    unsigned long long* csr_ev = (unsigned long long*)(hb + 3200000);   // 800,000 u64 (6.4 MB)
    unsigned long long* tmp    = csr_ev + 800000;             // 196*6144 u64 (9.63 MB)
    int* row_ptr          = (int*)(tmp + (size_t)NBUCK * REG_STRIDE);   // 50,001 (pad 50,048)
    int* gcursor          = row_ptr + 50048;                  // 256
    unsigned short* W1t   = (unsigned short*)(gcursor + 256); // 65,536 ushort

    hipLaunchKernelGGL(w1conv_k,   dim3(256),  dim3(256), 0, stream, W1, W1t, gcursor);
    hipLaunchKernelGGL(bucket1_k,  dim3(391),  dim3(256), 0, stream, esrc, edst, ev, gcursor, tmp);
    hipLaunchKernelGGL(bucket2_k,  dim3(NBUCK),dim3(256), 0, stream, gcursor, tmp, csr_ev, row_ptr);

    hipLaunchKernelGGL(gemm1_mfma, dim3(782),  dim3(256), 0, stream, x, W1t, pre1b);
    hipLaunchKernelGGL(spmm1_k,    dim3(12500),dim3(256), 0, stream, row_ptr, csr_ev, (const unsigned*)pre1b, hb);
    hipLaunchKernelGGL(gemm2_k,    dim3(1563), dim3(256), 0, stream, hb, W2, pre2b);
    hipLaunchKernelGGL(spmm2_k,    dim3(12500),dim3(256), 0, stream, row_ptr, csr_ev, (const unsigned*)pre2b, out);
}

// Round 9
// 169.889 us; speedup vs baseline: 1.1615x; 1.1615x over previous
//
#include <hip/hip_runtime.h>
#include <hip/hip_bf16.h>

#define N_NODES 50000
#define N_EDGES 800000
#define N_FEAT 512
#define HIDDEN 128
#define N_CLASSES 32

#define NBUCK 196        // coarse buckets: src>>8 (256-node regions)
#define REG_STRIDE 6144  // slots per region (mean 4081, sigma 64 -> 30+ sigma headroom)

typedef __attribute__((ext_vector_type(8))) short bf16x8;
typedef __attribute__((ext_vector_type(4))) float f32x4;

// round-to-nearest-even f32 -> bf16 bits
static __device__ __forceinline__ unsigned short f2bf(float f) {
    unsigned u = __float_as_uint(f);
    u += 0x7FFFu + ((u >> 16) & 1u);
    return (unsigned short)(u >> 16);
}
// unpack uint = (bf16_hi<<16)|bf16_lo
static __device__ __forceinline__ float bflo(unsigned u) { return __uint_as_float(u << 16); }
static __device__ __forceinline__ float bfhi(unsigned u) { return __uint_as_float(u & 0xFFFF0000u); }
static __device__ __forceinline__ unsigned pack2(float a, float b) {
    return (unsigned)f2bf(a) | ((unsigned)f2bf(b) << 16);
}

// ---------------- CSR build, phase 1: LDS-bucketed coarse scatter ----------------
// record: src(16) | dst(16)<<16 | val_bits<<32

__global__ __launch_bounds__(256) void bucket1_k(const int* __restrict__ src, const int* __restrict__ dst,
                                                 const float* __restrict__ val,
                                                 int* __restrict__ gcursor,
                                                 unsigned long long* __restrict__ tmp) {
    __shared__ int cnt[256];
    __shared__ int lstart[256];
    __shared__ int lcur[256];
    __shared__ int gbase[256];
    __shared__ unsigned long long buf[2048];   // 16 KB
    const int t = threadIdx.x;
    const int e0 = blockIdx.x * 2048;
    const int ne = min(2048, N_EDGES - e0);

    cnt[t] = 0;
    __syncthreads();

    unsigned long long rec[8];
    int rb[8];
#pragma unroll
    for (int j = 0; j < 8; ++j) {
        int p = j * 256 + t;
        rec[j] = 0; rb[j] = -1;
        if (p < ne) {
            int i = e0 + p;
            unsigned s = (unsigned)src[i];
            rec[j] = (unsigned long long)(s | ((unsigned)dst[i] << 16))
                   | ((unsigned long long)__float_as_uint(val[i]) << 32);
            int b = (int)(s >> 8);
            rb[j] = b;
            atomicAdd(&cnt[b], 1);
        }
    }
    __syncthreads();
    const int cv = cnt[t];
    // inclusive scan (Hillis-Steele)
    for (int off = 1; off < 256; off <<= 1) {
        int xv = (t >= off) ? cnt[t - off] : 0;
        __syncthreads();
        cnt[t] += xv;
        __syncthreads();
    }
    lstart[t] = cnt[t] - cv;
    lcur[t]   = cnt[t] - cv;
    if (t < NBUCK) gbase[t] = atomicAdd(&gcursor[t], cv);
    __syncthreads();
    // place records bucket-grouped into LDS
#pragma unroll
    for (int j = 0; j < 8; ++j) {
        if (rb[j] >= 0) {
            int pos = atomicAdd(&lcur[rb[j]], 1);
            buf[pos] = rec[j];
        }
    }
    __syncthreads();
    // burst write-out: consecutive p within a bucket -> consecutive global slots
#pragma unroll
    for (int j = 0; j < 8; ++j) {
        int p = j * 256 + t;
        if (p < ne) {
            unsigned long long r = buf[p];
            int b = (int)((r & 0xFFFFu) >> 8);
            int tgt = gbase[b] + (p - lstart[b]);
            tmp[(size_t)b * REG_STRIDE + tgt] = r;
        }
    }
}

// ---------------- CSR build, phase 2: per-region local sort + row_ptr ----------------

__global__ __launch_bounds__(256) void bucket2_k(const int* __restrict__ gcursor,
                                                 const unsigned long long* __restrict__ tmp,
                                                 unsigned long long* __restrict__ csr_ev,
                                                 int* __restrict__ row_ptr) {
    __shared__ int lcnt[256];
    __shared__ int lcur[256];
    __shared__ int cnts[NBUCK];
    __shared__ int base_s;
    const int b = blockIdx.x;
    const int t = threadIdx.x;
    if (t < NBUCK) cnts[t] = gcursor[t];
    lcnt[t] = 0;
    __syncthreads();
    const int nb = cnts[b];
    if (t == 0) {
        int s = 0;
        for (int r = 0; r < b; ++r) s += cnts[r];
        base_s = s;
    }
    const unsigned long long* reg = tmp + (size_t)b * REG_STRIDE;
    __syncthreads();
    // pass 1: per-node counts (local node = rec & 255, regions are 256-aligned)
    for (int p = t; p < nb; p += 256)
        atomicAdd(&lcnt[(int)(reg[p] & 0xFFu)], 1);
    __syncthreads();
    const int cv = lcnt[t];
    for (int off = 1; off < 256; off <<= 1) {
        int xv = (t >= off) ? lcnt[t - off] : 0;
        __syncthreads();
        lcnt[t] += xv;
        __syncthreads();
    }
    const int abs_start = base_s + lcnt[t] - cv;
    lcur[t] = abs_start;
    int node = b * 256 + t;
    if (node <= N_NODES) row_ptr[node] = abs_start;
    __syncthreads();
    // pass 2: place (L2-hot ~33KB window)
    for (int p = t; p < nb; p += 256) {
        unsigned long long r = reg[p];
        int pos = atomicAdd(&lcur[(int)(r & 0xFFu)], 1);
        csr_ev[pos] = ((r >> 16) & 0xFFFFull) | (r & 0xFFFFFFFF00000000ull);
    }
}

// ---------------- W1 transpose + bf16 (+ gcursor zero): W1[512][128] -> W1t[128][512] ----------------

__global__ __launch_bounds__(256) void w1conv_k(const float* __restrict__ W1,
                                                unsigned short* __restrict__ W1t,
                                                int* __restrict__ gcursor) {
    if (blockIdx.x == 0 && threadIdx.x < NBUCK) gcursor[threadIdx.x] = 0;
    int id = blockIdx.x * 256 + threadIdx.x;   // 65536
    int c = id >> 9;          // 0..127
    int k = id & 511;         // 0..511
    W1t[(size_t)c * N_FEAT + k] = f2bf(W1[(size_t)k * HIDDEN + c]);
}

// ---------------- GEMM1 via bf16 MFMA: B-in-LDS (staged once) + barrier-free K-loop ----------------
// Block: 512 threads = 8 waves, covers 128 rows x 64 cols. Grid = 391 row-tiles x 2 col-halves.
// Stage: 64-col B half (64x512 bf16 = 64KB) into LDS in MFMA-fragment order -> ONE barrier.
// K-loop (no barriers): A streamed from x (lane owns a row; a0+a1 cover full 128B lines),
// depth-1 A prefetch in regs; B via contiguous-per-lane ds_read_b128 (conflict-free).

__global__ __launch_bounds__(512, 2) void gemm1_mfma(const float* __restrict__ x,
                                                     const unsigned short* __restrict__ W1t,
                                                     unsigned short* __restrict__ pre1b) {
    __shared__ short Bs[4096 * 8];   // 64 KB, fragment chunks: cid = (kstep*4+n)*64 + lane

    const int t = threadIdx.x;
    const int w = t >> 6;            // 0..7: row group
    const int l = t & 63;
    const int l15 = l & 15;
    const int lhi = l >> 4;
    const int brow0 = (blockIdx.x >> 1) * 128;
    const int c0 = (blockIdx.x & 1) * 64;

    // stage B fragments: 4096 chunks of 16B, 8 per thread (from L2-hot 128KB W1t)
#pragma unroll
    for (int j = 0; j < 8; ++j) {
        int cid = j * 512 + t;
        int fi = cid >> 6;                 // 0..63 = kstep*4+n
        int ln = cid & 63;
        int col = c0 + (fi & 3) * 16 + (ln & 15);
        int kof = (fi >> 2) * 32 + (ln >> 4) * 8;
        *(bf16x8*)&Bs[cid * 8] = *(const bf16x8*)(W1t + (size_t)col * N_FEAT + kof);
    }
    __syncthreads();   // the only barrier

    int r = brow0 + w * 16 + l15;
    if (r > N_NODES - 1) r = N_NODES - 1;          // clamp (stores guarded)
    const float* xr = x + (size_t)r * N_FEAT + lhi * 8;

    f32x4 acc[4];
#pragma unroll
    for (int n = 0; n < 4; ++n) acc[n] = (f32x4){0.f, 0.f, 0.f, 0.f};

    float4 a0 = *(const float4*)(xr);
    float4 a1 = *(const float4*)(xr + 4);
#pragma unroll
    for (int ks = 0; ks < 16; ++ks) {
        float4 c0v = a0, c1v = a1;
        if (ks < 15) {                              // depth-1 prefetch
            a0 = *(const float4*)(xr + (ks + 1) * 32);
            a1 = *(const float4*)(xr + (ks + 1) * 32 + 4);
        }
        bf16x8 af;
        af[0] = (short)f2bf(c0v.x); af[1] = (short)f2bf(c0v.y);
        af[2] = (short)f2bf(c0v.z); af[3] = (short)f2bf(c0v.w);
        af[4] = (short)f2bf(c1v.x); af[5] = (short)f2bf(c1v.y);
        af[6] = (short)f2bf(c1v.z); af[7] = (short)f2bf(c1v.w);
        const short* bp = &Bs[(ks * 4) * 512 + l * 8];
#pragma unroll
        for (int n = 0; n < 4; ++n) {
            bf16x8 bf = *(const bf16x8*)(bp + n * 512);
            acc[n] = __builtin_amdgcn_mfma_f32_16x16x32_bf16(af, bf, acc[n], 0, 0, 0);
        }
    }
    // epilogue: C/D layout col=lane&15, row=(lane>>4)*4+reg
    const int r0 = brow0 + w * 16 + lhi * 4;
    unsigned short* obase = pre1b + (size_t)r0 * HIDDEN + c0 + l15;
#pragma unroll
    for (int n = 0; n < 4; ++n)
#pragma unroll
        for (int j = 0; j < 4; ++j)
            if (r0 + j < N_NODES) obase[(size_t)j * HIDDEN + n * 16] = f2bf(acc[n][j]);
}

// ---------------- SpMM1: hb = bf16(relu(A @ pre1)), one wave per node, 1 uint (2 feats)/lane ----------------

__global__ __launch_bounds__(256) void spmm1_k(const int* __restrict__ rp,
                                               const unsigned long long* __restrict__ ce,
                                               const unsigned* __restrict__ P,
                                               unsigned* __restrict__ hb) {
    const int g = threadIdx.x >> 6;
    const int lane = threadIdx.x & 63;
    const int node = blockIdx.x * 4 + g;
    if (node >= N_NODES) return;
    const int s = rp[node], e = rp[node + 1];
    float2 a0; a0.x = 0.f; a0.y = 0.f;
    float2 a1; a1.x = 0.f; a1.y = 0.f;
    int i = s;
    for (; i + 2 <= e; i += 2) {
        unsigned long long e0 = ce[i], e1 = ce[i + 1];
        int d0 = (int)(unsigned)e0, d1 = (int)(unsigned)e1;
        float v0 = __uint_as_float((unsigned)(e0 >> 32));
        float v1 = __uint_as_float((unsigned)(e1 >> 32));
        unsigned u0 = P[(size_t)d0 * 64 + lane];
        unsigned u1 = P[(size_t)d1 * 64 + lane];
        a0.x += v0 * bflo(u0); a0.y += v0 * bfhi(u0);
        a1.x += v1 * bflo(u1); a1.y += v1 * bfhi(u1);
    }
    if (i < e) {
        unsigned long long e0 = ce[i];
        int d0 = (int)(unsigned)e0;
        float v0 = __uint_as_float((unsigned)(e0 >> 32));
        unsigned u0 = P[(size_t)d0 * 64 + lane];
        a0.x += v0 * bflo(u0); a0.y += v0 * bfhi(u0);
    }
    a0.x += a1.x; a0.y += a1.y;
    a0.x = a0.x > 0.f ? a0.x : 0.f;
    a0.y = a0.y > 0.f ? a0.y : 0.f;
    hb[(size_t)node * 64 + lane] = pack2(a0.x, a0.y);
}

// ---------------- GEMM2: pre2b[50000,32] = bf16(h @ W2) ----------------

__global__ __launch_bounds__(256) void gemm2_k(const unsigned* __restrict__ hb,
                                               const float* __restrict__ W2,
                                               unsigned short* __restrict__ pre2b) {
    __shared__ float hs[32][132];
    __shared__ float w2s[HIDDEN][N_CLASSES];
    const int t = threadIdx.x;
    const int row0 = blockIdx.x * 32;
#pragma unroll
    for (int j = 0; j < 4; ++j) {        // W2: 1024 float4
        int f = j * 256 + t;
        int r = f >> 3;
        int c = (f & 7) << 2;
        *(float4*)&w2s[r][c] = *(const float4*)(W2 + (size_t)r * N_CLASSES + c);
    }
#pragma unroll
    for (int j = 0; j < 2; ++j) {        // h tile: 32 rows x 64 uints = 2048 uints
        int f = j * 256 + t;
        int r = f >> 4;                  // 0..31
        int cu = (f & 15) << 2;          // uint col 0..60 step 4
        int grr = row0 + r;
        if (grr >= N_NODES) grr = N_NODES - 1;
        uint4 u = *(const uint4*)(hb + (size_t)grr * 64 + cu);
        hs[r][2 * cu + 0] = bflo(u.x); hs[r][2 * cu + 1] = bfhi(u.x);
        hs[r][2 * cu + 2] = bflo(u.y); hs[r][2 * cu + 3] = bfhi(u.y);
        hs[r][2 * cu + 4] = bflo(u.z); hs[r][2 * cu + 5] = bfhi(u.z);
        hs[r][2 * cu + 6] = bflo(u.w); hs[r][2 * cu + 7] = bfhi(u.w);
    }
    __syncthreads();
    const int r = t >> 3;
    const int c = (t & 7) << 2;
    float4 acc; acc.x = acc.y = acc.z = acc.w = 0.f;
#pragma unroll 16
    for (int kk = 0; kk < HIDDEN; ++kk) {
        float a = hs[r][kk];
        float4 b = *(const float4*)&w2s[kk][c];
        acc.x += a * b.x; acc.y += a * b.y; acc.z += a * b.z; acc.w += a * b.w;
    }
    int grr = row0 + r;
    if (grr < N_NODES) {
        uint2 o;
        o.x = pack2(acc.x, acc.y);
        o.y = pack2(acc.z, acc.w);
        *(uint2*)&pre2b[(size_t)grr * N_CLASSES + c] = o;
    }
}

// ---------------- SpMM2: out = A @ pre2 ; 16 lanes/edge, 4 edges/iter ----------------

__global__ __launch_bounds__(256) void spmm2_k(const int* __restrict__ rp,
                                               const unsigned long long* __restrict__ ce,
                                               const unsigned* __restrict__ P2,
                                               float* __restrict__ out) {
    const int g = threadIdx.x >> 6;
    const int lane = threadIdx.x & 63;
    const int node = blockIdx.x * 4 + g;
    if (node >= N_NODES) return;
    const int s = rp[node], e = rp[node + 1];
    const int f2 = lane & 15;      // uint index: feats 2*f2, 2*f2+1
    const int par = lane >> 4;     // 0..3
    float ax = 0.f, ay = 0.f;
    for (int i = s + par; i < e; i += 4) {
        unsigned long long ed = ce[i];
        int dst = (int)(unsigned)ed;
        float v = __uint_as_float((unsigned)(ed >> 32));
        unsigned u = P2[(size_t)dst * 16 + f2];
        ax += v * bflo(u);
        ay += v * bfhi(u);
    }
    ax += __shfl_xor(ax, 16); ay += __shfl_xor(ay, 16);
    ax += __shfl_xor(ax, 32); ay += __shfl_xor(ay, 32);
    if (lane < 16) {
        float2 o; o.x = ax; o.y = ay;
        ((float2*)out)[(size_t)node * 16 + f2] = o;
    }
}

// ---------------- launch ----------------

extern "C" void kernel_launch(void* const* d_in, const int* in_sizes, int n_in,
                              void* d_out, int out_size, void* d_ws, size_t ws_size,
                              hipStream_t stream) {
    const float* x    = (const float*)d_in[0];
    const int* esrc   = (const int*)d_in[1];
    const int* edst   = (const int*)d_in[2];
    const float* ev   = (const float*)d_in[3];
    const float* W1   = (const float*)d_in[4];
    const float* W2   = (const float*)d_in[5];
    float* out        = (float*)d_out;

    // workspace layout; pre2b aliases pre1b (pre1b dead after spmm1)
    unsigned short* pre1b = (unsigned short*)d_ws;            // 6,400,000 ushort (12.8 MB)
    unsigned* hb          = (unsigned*)(pre1b + 6400000);     // 3,200,000 uint (12.8 MB)
    unsigned short* pre2b = pre1b;                            // alias
    unsigned long long* csr_ev = (unsigned long long*)(hb + 3200000);   // 800,000 u64 (6.4 MB)
    unsigned long long* tmp    = csr_ev + 800000;             // 196*6144 u64 (9.63 MB)
    int* row_ptr          = (int*)(tmp + (size_t)NBUCK * REG_STRIDE);   // 50,001 (pad 50,048)
    int* gcursor          = row_ptr + 50048;                  // 256
    unsigned short* W1t   = (unsigned short*)(gcursor + 256); // 65,536 ushort

    hipLaunchKernelGGL(w1conv_k,   dim3(256),  dim3(256), 0, stream, W1, W1t, gcursor);
    hipLaunchKernelGGL(bucket1_k,  dim3(391),  dim3(256), 0, stream, esrc, edst, ev, gcursor, tmp);
    hipLaunchKernelGGL(bucket2_k,  dim3(NBUCK),dim3(256), 0, stream, gcursor, tmp, csr_ev, row_ptr);

    hipLaunchKernelGGL(gemm1_mfma, dim3(782),  dim3(512), 0, stream, x, W1t, pre1b);
    hipLaunchKernelGGL(spmm1_k,    dim3(12500),dim3(256), 0, stream, row_ptr, csr_ev, (const unsigned*)pre1b, hb);
    hipLaunchKernelGGL(gemm2_k,    dim3(1563), dim3(256), 0, stream, hb, W2, pre2b);
    hipLaunchKernelGGL(spmm2_k,    dim3(12500),dim3(256), 0, stream, row_ptr, csr_ev, (const unsigned*)pre2b, out);
}

// Round 10
// 166.565 us; speedup vs baseline: 1.1846x; 1.0200x over previous
//
#include <hip/hip_runtime.h>
#include <hip/hip_bf16.h>

#define N_NODES 50000
#define N_EDGES 800000
#define N_FEAT 512
#define HIDDEN 128
#define N_CLASSES 32

#define NBUCK 196        // coarse buckets: src>>8 (256-node regions)
#define REG_STRIDE 6144  // slots per region (mean 4081, sigma 64 -> 30+ sigma headroom)

typedef __attribute__((ext_vector_type(8))) short bf16x8;
typedef __attribute__((ext_vector_type(4))) float f32x4;

// round-to-nearest-even f32 -> bf16 bits (cold paths)
static __device__ __forceinline__ unsigned short f2bf(float f) {
    unsigned u = __float_as_uint(f);
    u += 0x7FFFu + ((u >> 16) & 1u);
    return (unsigned short)(u >> 16);
}
// unpack uint = (bf16_hi<<16)|bf16_lo
static __device__ __forceinline__ float bflo(unsigned u) { return __uint_as_float(u << 16); }
static __device__ __forceinline__ float bfhi(unsigned u) { return __uint_as_float(u & 0xFFFF0000u); }
// HW packed cvt: one v_cvt_pk_bf16_f32 (RNE)
static __device__ __forceinline__ unsigned pack2(float a, float b) {
    union { __hip_bfloat162 h; unsigned u; } c;
    c.h = __float22bfloat162_rn(make_float2(a, b));
    return c.u;
}

// ---------------- CSR build, phase 1: LDS-bucketed coarse scatter ----------------
// record: src(16) | dst(16)<<16 | val_bits<<32

__global__ __launch_bounds__(256) void bucket1_k(const int* __restrict__ src, const int* __restrict__ dst,
                                                 const float* __restrict__ val,
                                                 int* __restrict__ gcursor,
                                                 unsigned long long* __restrict__ tmp) {
    __shared__ int cnt[256];
    __shared__ int lstart[256];
    __shared__ int lcur[256];
    __shared__ int gbase[256];
    __shared__ unsigned long long buf[2048];   // 16 KB
    const int t = threadIdx.x;
    const int e0 = blockIdx.x * 2048;
    const int ne = min(2048, N_EDGES - e0);

    cnt[t] = 0;
    __syncthreads();

    unsigned long long rec[8];
    int rb[8];
#pragma unroll
    for (int j = 0; j < 8; ++j) {
        int p = j * 256 + t;
        rec[j] = 0; rb[j] = -1;
        if (p < ne) {
            int i = e0 + p;
            unsigned s = (unsigned)src[i];
            rec[j] = (unsigned long long)(s | ((unsigned)dst[i] << 16))
                   | ((unsigned long long)__float_as_uint(val[i]) << 32);
            int b = (int)(s >> 8);
            rb[j] = b;
            atomicAdd(&cnt[b], 1);
        }
    }
    __syncthreads();
    const int cv = cnt[t];
    // inclusive scan (Hillis-Steele)
    for (int off = 1; off < 256; off <<= 1) {
        int xv = (t >= off) ? cnt[t - off] : 0;
        __syncthreads();
        cnt[t] += xv;
        __syncthreads();
    }
    lstart[t] = cnt[t] - cv;
    lcur[t]   = cnt[t] - cv;
    if (t < NBUCK) gbase[t] = atomicAdd(&gcursor[t], cv);
    __syncthreads();
    // place records bucket-grouped into LDS
#pragma unroll
    for (int j = 0; j < 8; ++j) {
        if (rb[j] >= 0) {
            int pos = atomicAdd(&lcur[rb[j]], 1);
            buf[pos] = rec[j];
        }
    }
    __syncthreads();
    // burst write-out: consecutive p within a bucket -> consecutive global slots
#pragma unroll
    for (int j = 0; j < 8; ++j) {
        int p = j * 256 + t;
        if (p < ne) {
            unsigned long long r = buf[p];
            int b = (int)((r & 0xFFFFu) >> 8);
            int tgt = gbase[b] + (p - lstart[b]);
            tmp[(size_t)b * REG_STRIDE + tgt] = r;
        }
    }
}

// ---------------- CSR build, phase 2: per-region local sort + row_ptr ----------------

__global__ __launch_bounds__(256) void bucket2_k(const int* __restrict__ gcursor,
                                                 const unsigned long long* __restrict__ tmp,
                                                 unsigned long long* __restrict__ csr_ev,
                                                 int* __restrict__ row_ptr) {
    __shared__ int lcnt[256];
    __shared__ int lcur[256];
    __shared__ int cnts[NBUCK];
    __shared__ int base_s;
    const int b = blockIdx.x;
    const int t = threadIdx.x;
    if (t < NBUCK) cnts[t] = gcursor[t];
    lcnt[t] = 0;
    __syncthreads();
    const int nb = cnts[b];
    if (t == 0) {
        int s = 0;
        for (int r = 0; r < b; ++r) s += cnts[r];
        base_s = s;
    }
    const unsigned long long* reg = tmp + (size_t)b * REG_STRIDE;
    __syncthreads();
    // pass 1: per-node counts (local node = rec & 255, regions are 256-aligned)
    for (int p = t; p < nb; p += 256)
        atomicAdd(&lcnt[(int)(reg[p] & 0xFFu)], 1);
    __syncthreads();
    const int cv = lcnt[t];
    for (int off = 1; off < 256; off <<= 1) {
        int xv = (t >= off) ? lcnt[t - off] : 0;
        __syncthreads();
        lcnt[t] += xv;
        __syncthreads();
    }
    const int abs_start = base_s + lcnt[t] - cv;
    lcur[t] = abs_start;
    int node = b * 256 + t;
    if (node <= N_NODES) row_ptr[node] = abs_start;
    __syncthreads();
    // pass 2: place (L2-hot ~33KB window)
    for (int p = t; p < nb; p += 256) {
        unsigned long long r = reg[p];
        int pos = atomicAdd(&lcur[(int)(r & 0xFFu)], 1);
        csr_ev[pos] = ((r >> 16) & 0xFFFFull) | (r & 0xFFFFFFFF00000000ull);
    }
}

// ---------------- W1 transpose + bf16 (+ gcursor zero): W1[512][128] -> W1t[128][512] ----------------

__global__ __launch_bounds__(256) void w1conv_k(const float* __restrict__ W1,
                                                unsigned short* __restrict__ W1t,
                                                int* __restrict__ gcursor) {
    if (blockIdx.x == 0 && threadIdx.x < NBUCK) gcursor[threadIdx.x] = 0;
    int id = blockIdx.x * 256 + threadIdx.x;   // 65536
    int c = id >> 9;          // 0..127
    int k = id & 511;         // 0..511
    W1t[(size_t)c * N_FEAT + k] = f2bf(W1[(size_t)k * HIDDEN + c]);
}

// ---------------- GEMM1 via bf16 MFMA: global_load_lds DMA + 2-phase double buffer ----------------
// Tile 64 rows x 128 cols (x read ONCE), BK=64, 8 K-iters, 256 threads / 4 waves.
// LDS fragment-chunk layout (1 KB chunks, lane-contiguous 16B): satisfies glds linear-dest
// AND gives conflict-floor ds_read_b128. A stays f32 in LDS; cvt at fragment build via
// v_cvt_pk_bf16_f32. One barrier per iteration (stage next || compute cur).
// LDS: A 2x16KB + B 2x16KB = 64 KB -> 2 blocks/CU.

__global__ __launch_bounds__(256, 2) void gemm1_mfma(const float* __restrict__ x,
                                                     const unsigned short* __restrict__ W1t,
                                                     unsigned short* __restrict__ pre1b) {
    __shared__ char lds[65536];   // [0,32K) = A bufs, [32K,64K) = B bufs

    const int t = threadIdx.x;
    const int w = t >> 6;            // wave 0..3 = col quarter
    const int l = t & 63;
    const int l15 = l & 15;
    const int lhi = l >> 4;
    const int brow0 = blockIdx.x * 64;

    f32x4 acc[4][2];
#pragma unroll
    for (int m = 0; m < 4; ++m)
#pragma unroll
        for (int n = 0; n < 2; ++n) acc[m][n] = (f32x4){0.f, 0.f, 0.f, 0.f};

    // ---- staging: 8 glds calls, each wave writes 4 chunks of 1 KB ----
    // A chunk c = (m*2+ks)*2+half : lane ln holds rows brow0+m*16+(ln&15),
    //   k = ks*32+(ln>>4)*8+half*4 .. +4 floats (16 B)
    // B chunk c = ks*8+cf          : lane ln holds col cf*16+(ln&15),
    //   k = ks*32+(ln>>4)*8 .. +8 shorts (16 B)
#define STAGE(k0v, abuf, bbuf)                                                              \
    {                                                                                       \
        _Pragma("unroll")                                                                   \
        for (int j = 0; j < 4; ++j) {                                                       \
            int c = j * 4 + w;                                                              \
            int m_ = c >> 2, ks_ = (c >> 1) & 1, hf_ = c & 1;                               \
            int row = brow0 + m_ * 16 + l15;                                                \
            if (row > N_NODES - 1) row = N_NODES - 1;                                       \
            int k = (k0v) + ks_ * 32 + lhi * 8 + hf_ * 4;                                   \
            __builtin_amdgcn_global_load_lds(x + (size_t)row * N_FEAT + k,                  \
                                             (float*)(lds + (abuf) + c * 1024), 16, 0, 0); \
        }                                                                                   \
        _Pragma("unroll")                                                                   \
        for (int j = 0; j < 4; ++j) {                                                       \
            int c = j * 4 + w;                                                              \
            int cf_ = c & 7, ks_ = c >> 3;                                                  \
            int col = cf_ * 16 + l15;                                                       \
            int k = (k0v) + ks_ * 32 + lhi * 8;                                             \
            __builtin_amdgcn_global_load_lds(W1t + (size_t)col * N_FEAT + k,                \
                                             (unsigned short*)(lds + (bbuf) + c * 1024),    \
                                             16, 0, 0);                                     \
        }                                                                                   \
    }

    STAGE(0, 0, 32768);
    int cur = 0;
    for (int it = 0; it < 8; ++it) {
        __syncthreads();   // buf[cur] staged (vmcnt drained); prev compute done
        if (it < 7) STAGE((it + 1) * 64, (cur ^ 1) * 16384, 32768 + (cur ^ 1) * 16384);
        const char* Ab = lds + cur * 16384;
        const char* Bb = lds + 32768 + cur * 16384;
        // B fragments for this wave (cols w*32 + n*16)
        bf16x8 bfr[2][2];
#pragma unroll
        for (int ks = 0; ks < 2; ++ks)
#pragma unroll
            for (int n = 0; n < 2; ++n)
                bfr[ks][n] = *(const bf16x8*)(Bb + (ks * 8 + w * 2 + n) * 1024 + l * 16);
#pragma unroll
        for (int m = 0; m < 4; ++m) {
#pragma unroll
            for (int ks = 0; ks < 2; ++ks) {
                int cb = ((m * 2 + ks) * 2) * 1024;
                float4 alo = *(const float4*)(Ab + cb + l * 16);
                float4 ahi = *(const float4*)(Ab + cb + 1024 + l * 16);
                union { bf16x8 v; __hip_bfloat162 h[4]; } u;
                u.h[0] = __float22bfloat162_rn(make_float2(alo.x, alo.y));
                u.h[1] = __float22bfloat162_rn(make_float2(alo.z, alo.w));
                u.h[2] = __float22bfloat162_rn(make_float2(ahi.x, ahi.y));
                u.h[3] = __float22bfloat162_rn(make_float2(ahi.z, ahi.w));
                acc[m][0] = __builtin_amdgcn_mfma_f32_16x16x32_bf16(u.v, bfr[ks][0], acc[m][0], 0, 0, 0);
                acc[m][1] = __builtin_amdgcn_mfma_f32_16x16x32_bf16(u.v, bfr[ks][1], acc[m][1], 0, 0, 0);
            }
        }
        cur ^= 1;
    }
#undef STAGE
    // epilogue: C/D layout col=lane&15, row=(lane>>4)*4+reg ; write bf16
#pragma unroll
    for (int m = 0; m < 4; ++m)
#pragma unroll
        for (int n = 0; n < 2; ++n) {
            int col = w * 32 + n * 16 + l15;
#pragma unroll
            for (int j = 0; j < 4; ++j) {
                int r = brow0 + m * 16 + lhi * 4 + j;
                if (r < N_NODES) pre1b[(size_t)r * HIDDEN + col] = f2bf(acc[m][n][j]);
            }
        }
}

// ---------------- SpMM1: hb = bf16(relu(A @ pre1)), one wave per node, 1 uint (2 feats)/lane ----------------

__global__ __launch_bounds__(256) void spmm1_k(const int* __restrict__ rp,
                                               const unsigned long long* __restrict__ ce,
                                               const unsigned* __restrict__ P,
                                               unsigned* __restrict__ hb) {
    const int g = threadIdx.x >> 6;
    const int lane = threadIdx.x & 63;
    const int node = blockIdx.x * 4 + g;
    if (node >= N_NODES) return;
    const int s = rp[node], e = rp[node + 1];
    float2 a0; a0.x = 0.f; a0.y = 0.f;
    float2 a1; a1.x = 0.f; a1.y = 0.f;
    int i = s;
    for (; i + 2 <= e; i += 2) {
        unsigned long long e0 = ce[i], e1 = ce[i + 1];
        int d0 = (int)(unsigned)e0, d1 = (int)(unsigned)e1;
        float v0 = __uint_as_float((unsigned)(e0 >> 32));
        float v1 = __uint_as_float((unsigned)(e1 >> 32));
        unsigned u0 = P[(size_t)d0 * 64 + lane];
        unsigned u1 = P[(size_t)d1 * 64 + lane];
        a0.x += v0 * bflo(u0); a0.y += v0 * bfhi(u0);
        a1.x += v1 * bflo(u1); a1.y += v1 * bfhi(u1);
    }
    if (i < e) {
        unsigned long long e0 = ce[i];
        int d0 = (int)(unsigned)e0;
        float v0 = __uint_as_float((unsigned)(e0 >> 32));
        unsigned u0 = P[(size_t)d0 * 64 + lane];
        a0.x += v0 * bflo(u0); a0.y += v0 * bfhi(u0);
    }
    a0.x += a1.x; a0.y += a1.y;
    a0.x = a0.x > 0.f ? a0.x : 0.f;
    a0.y = a0.y > 0.f ? a0.y : 0.f;
    hb[(size_t)node * 64 + lane] = pack2(a0.x, a0.y);
}

// ---------------- GEMM2: pre2b[50000,32] = bf16(h @ W2) ----------------

__global__ __launch_bounds__(256) void gemm2_k(const unsigned* __restrict__ hb,
                                               const float* __restrict__ W2,
                                               unsigned short* __restrict__ pre2b) {
    __shared__ float hs[32][132];
    __shared__ float w2s[HIDDEN][N_CLASSES];
    const int t = threadIdx.x;
    const int row0 = blockIdx.x * 32;
#pragma unroll
    for (int j = 0; j < 4; ++j) {        // W2: 1024 float4
        int f = j * 256 + t;
        int r = f >> 3;
        int c = (f & 7) << 2;
        *(float4*)&w2s[r][c] = *(const float4*)(W2 + (size_t)r * N_CLASSES + c);
    }
#pragma unroll
    for (int j = 0; j < 2; ++j) {        // h tile: 32 rows x 64 uints = 2048 uints
        int f = j * 256 + t;
        int r = f >> 4;                  // 0..31
        int cu = (f & 15) << 2;          // uint col 0..60 step 4
        int grr = row0 + r;
        if (grr >= N_NODES) grr = N_NODES - 1;
        uint4 u = *(const uint4*)(hb + (size_t)grr * 64 + cu);
        hs[r][2 * cu + 0] = bflo(u.x); hs[r][2 * cu + 1] = bfhi(u.x);
        hs[r][2 * cu + 2] = bflo(u.y); hs[r][2 * cu + 3] = bfhi(u.y);
        hs[r][2 * cu + 4] = bflo(u.z); hs[r][2 * cu + 5] = bfhi(u.z);
        hs[r][2 * cu + 6] = bflo(u.w); hs[r][2 * cu + 7] = bfhi(u.w);
    }
    __syncthreads();
    const int r = t >> 3;
    const int c = (t & 7) << 2;
    float4 acc; acc.x = acc.y = acc.z = acc.w = 0.f;
#pragma unroll 16
    for (int kk = 0; kk < HIDDEN; ++kk) {
        float a = hs[r][kk];
        float4 b = *(const float4*)&w2s[kk][c];
        acc.x += a * b.x; acc.y += a * b.y; acc.z += a * b.z; acc.w += a * b.w;
    }
    int grr = row0 + r;
    if (grr < N_NODES) {
        uint2 o;
        o.x = pack2(acc.x, acc.y);
        o.y = pack2(acc.z, acc.w);
        *(uint2*)&pre2b[(size_t)grr * N_CLASSES + c] = o;
    }
}

// ---------------- SpMM2: out = A @ pre2 ; 16 lanes/edge, 4 edges/iter ----------------

__global__ __launch_bounds__(256) void spmm2_k(const int* __restrict__ rp,
                                               const unsigned long long* __restrict__ ce,
                                               const unsigned* __restrict__ P2,
                                               float* __restrict__ out) {
    const int g = threadIdx.x >> 6;
    const int lane = threadIdx.x & 63;
    const int node = blockIdx.x * 4 + g;
    if (node >= N_NODES) return;
    const int s = rp[node], e = rp[node + 1];
    const int f2 = lane & 15;      // uint index: feats 2*f2, 2*f2+1
    const int par = lane >> 4;     // 0..3
    float ax = 0.f, ay = 0.f;
    for (int i = s + par; i < e; i += 4) {
        unsigned long long ed = ce[i];
        int dst = (int)(unsigned)ed;
        float v = __uint_as_float((unsigned)(ed >> 32));
        unsigned u = P2[(size_t)dst * 16 + f2];
        ax += v * bflo(u);
        ay += v * bfhi(u);
    }
    ax += __shfl_xor(ax, 16); ay += __shfl_xor(ay, 16);
    ax += __shfl_xor(ax, 32); ay += __shfl_xor(ay, 32);
    if (lane < 16) {
        float2 o; o.x = ax; o.y = ay;
        ((float2*)out)[(size_t)node * 16 + f2] = o;
    }
}

// ---------------- launch ----------------

extern "C" void kernel_launch(void* const* d_in, const int* in_sizes, int n_in,
                              void* d_out, int out_size, void* d_ws, size_t ws_size,
                              hipStream_t stream) {
    const float* x    = (const float*)d_in[0];
    const int* esrc   = (const int*)d_in[1];
    const int* edst   = (const int*)d_in[2];
    const float* ev   = (const float*)d_in[3];
    const float* W1   = (const float*)d_in[4];
    const float* W2   = (const float*)d_in[5];
    float* out        = (float*)d_out;

    // workspace layout; pre2b aliases pre1b (pre1b dead after spmm1)
    unsigned short* pre1b = (unsigned short*)d_ws;            // 6,400,000 ushort (12.8 MB)
    unsigned* hb          = (unsigned*)(pre1b + 6400000);     // 3,200,000 uint (12.8 MB)
    unsigned short* pre2b = pre1b;                            // alias
    unsigned long long* csr_ev = (unsigned long long*)(hb + 3200000);   // 800,000 u64 (6.4 MB)
    unsigned long long* tmp    = csr_ev + 800000;             // 196*6144 u64 (9.63 MB)
    int* row_ptr          = (int*)(tmp + (size_t)NBUCK * REG_STRIDE);   // 50,001 (pad 50,048)
    int* gcursor          = row_ptr + 50048;                  // 256
    unsigned short* W1t   = (unsigned short*)(gcursor + 256); // 65,536 ushort

    hipLaunchKernelGGL(w1conv_k,   dim3(256),  dim3(256), 0, stream, W1, W1t, gcursor);
    hipLaunchKernelGGL(bucket1_k,  dim3(391),  dim3(256), 0, stream, esrc, edst, ev, gcursor, tmp);
    hipLaunchKernelGGL(bucket2_k,  dim3(NBUCK),dim3(256), 0, stream, gcursor, tmp, csr_ev, row_ptr);

    hipLaunchKernelGGL(gemm1_mfma, dim3(782),  dim3(256), 0, stream, x, W1t, pre1b);
    hipLaunchKernelGGL(spmm1_k,    dim3(12500),dim3(256), 0, stream, row_ptr, csr_ev, (const unsigned*)pre1b, hb);
    hipLaunchKernelGGL(gemm2_k,    dim3(1563), dim3(256), 0, stream, hb, W2, pre2b);
    hipLaunchKernelGGL(spmm2_k,    dim3(12500),dim3(256), 0, stream, row_ptr, csr_ev, (const unsigned*)pre2b, out);
}

// Round 11
// 153.642 us; speedup vs baseline: 1.2843x; 1.0841x over previous
//
#include <hip/hip_runtime.h>
#include <hip/hip_bf16.h>

#define N_NODES 50000
#define N_EDGES 800000
#define N_FEAT 512
#define HIDDEN 128
#define N_CLASSES 32

#define NBUCK 196        // coarse buckets: src>>8 (256-node regions)
#define REG_STRIDE 6144  // slots per region (mean 4081, sigma 64 -> 30+ sigma headroom)

typedef __attribute__((ext_vector_type(8))) short bf16x8;
typedef __attribute__((ext_vector_type(4))) float f32x4;

// round-to-nearest-even f32 -> bf16 bits (cold paths)
static __device__ __forceinline__ unsigned short f2bf(float f) {
    unsigned u = __float_as_uint(f);
    u += 0x7FFFu + ((u >> 16) & 1u);
    return (unsigned short)(u >> 16);
}
// unpack uint = (bf16_hi<<16)|bf16_lo
static __device__ __forceinline__ float bflo(unsigned u) { return __uint_as_float(u << 16); }
static __device__ __forceinline__ float bfhi(unsigned u) { return __uint_as_float(u & 0xFFFF0000u); }
// HW packed cvt: one v_cvt_pk_bf16_f32 (RNE)
static __device__ __forceinline__ unsigned pack2(float a, float b) {
    union { __hip_bfloat162 h; unsigned u; } c;
    c.h = __float22bfloat162_rn(make_float2(a, b));
    return c.u;
}

// ---------------- CSR build, phase 1: LDS-bucketed coarse scatter ----------------
// record: src(16) | dst(16)<<16 | val_bits<<32

__global__ __launch_bounds__(256) void bucket1_k(const int* __restrict__ src, const int* __restrict__ dst,
                                                 const float* __restrict__ val,
                                                 int* __restrict__ gcursor,
                                                 unsigned long long* __restrict__ tmp) {
    __shared__ int cnt[256];
    __shared__ int lstart[256];
    __shared__ int lcur[256];
    __shared__ int gbase[256];
    __shared__ unsigned long long buf[2048];   // 16 KB
    const int t = threadIdx.x;
    const int e0 = blockIdx.x * 2048;
    const int ne = min(2048, N_EDGES - e0);

    cnt[t] = 0;
    __syncthreads();

    unsigned long long rec[8];
    int rb[8];
#pragma unroll
    for (int j = 0; j < 8; ++j) {
        int p = j * 256 + t;
        rec[j] = 0; rb[j] = -1;
        if (p < ne) {
            int i = e0 + p;
            unsigned s = (unsigned)src[i];
            rec[j] = (unsigned long long)(s | ((unsigned)dst[i] << 16))
                   | ((unsigned long long)__float_as_uint(val[i]) << 32);
            int b = (int)(s >> 8);
            rb[j] = b;
            atomicAdd(&cnt[b], 1);
        }
    }
    __syncthreads();
    const int cv = cnt[t];
    // inclusive scan (Hillis-Steele)
    for (int off = 1; off < 256; off <<= 1) {
        int xv = (t >= off) ? cnt[t - off] : 0;
        __syncthreads();
        cnt[t] += xv;
        __syncthreads();
    }
    lstart[t] = cnt[t] - cv;
    lcur[t]   = cnt[t] - cv;
    if (t < NBUCK) gbase[t] = atomicAdd(&gcursor[t], cv);
    __syncthreads();
    // place records bucket-grouped into LDS
#pragma unroll
    for (int j = 0; j < 8; ++j) {
        if (rb[j] >= 0) {
            int pos = atomicAdd(&lcur[rb[j]], 1);
            buf[pos] = rec[j];
        }
    }
    __syncthreads();
    // burst write-out: consecutive p within a bucket -> consecutive global slots
#pragma unroll
    for (int j = 0; j < 8; ++j) {
        int p = j * 256 + t;
        if (p < ne) {
            unsigned long long r = buf[p];
            int b = (int)((r & 0xFFFFu) >> 8);
            int tgt = gbase[b] + (p - lstart[b]);
            tmp[(size_t)b * REG_STRIDE + tgt] = r;
        }
    }
}

// ---------------- CSR build, phase 2: per-region local sort + row_ptr ----------------

__global__ __launch_bounds__(256) void bucket2_k(const int* __restrict__ gcursor,
                                                 const unsigned long long* __restrict__ tmp,
                                                 unsigned long long* __restrict__ csr_ev,
                                                 int* __restrict__ row_ptr) {
    __shared__ int lcnt[256];
    __shared__ int lcur[256];
    __shared__ int cnts[NBUCK];
    __shared__ int base_s;
    const int b = blockIdx.x;
    const int t = threadIdx.x;
    if (t < NBUCK) cnts[t] = gcursor[t];
    lcnt[t] = 0;
    __syncthreads();
    const int nb = cnts[b];
    if (t == 0) {
        int s = 0;
        for (int r = 0; r < b; ++r) s += cnts[r];
        base_s = s;
    }
    const unsigned long long* reg = tmp + (size_t)b * REG_STRIDE;
    __syncthreads();
    // pass 1: per-node counts (local node = rec & 255, regions are 256-aligned)
    for (int p = t; p < nb; p += 256)
        atomicAdd(&lcnt[(int)(reg[p] & 0xFFu)], 1);
    __syncthreads();
    const int cv = lcnt[t];
    for (int off = 1; off < 256; off <<= 1) {
        int xv = (t >= off) ? lcnt[t - off] : 0;
        __syncthreads();
        lcnt[t] += xv;
        __syncthreads();
    }
    const int abs_start = base_s + lcnt[t] - cv;
    lcur[t] = abs_start;
    int node = b * 256 + t;
    if (node <= N_NODES) row_ptr[node] = abs_start;
    __syncthreads();
    // pass 2: place (L2-hot ~33KB window)
    for (int p = t; p < nb; p += 256) {
        unsigned long long r = reg[p];
        int pos = atomicAdd(&lcur[(int)(r & 0xFFu)], 1);
        csr_ev[pos] = ((r >> 16) & 0xFFFFull) | (r & 0xFFFFFFFF00000000ull);
    }
}

// ---------------- W1 transpose + bf16 (+ gcursor zero): W1[512][128] -> W1t[128][512] ----------------

__global__ __launch_bounds__(256) void w1conv_k(const float* __restrict__ W1,
                                                unsigned short* __restrict__ W1t,
                                                int* __restrict__ gcursor) {
    if (blockIdx.x == 0 && threadIdx.x < NBUCK) gcursor[threadIdx.x] = 0;
    int id = blockIdx.x * 256 + threadIdx.x;   // 65536
    int c = id >> 9;          // 0..127
    int k = id & 511;         // 0..511
    W1t[(size_t)c * N_FEAT + k] = f2bf(W1[(size_t)k * HIDDEN + c]);
}

// ---------------- GEMM1: ALL of W1t (128 KB bf16) in LDS; per-wave independent streaming ----------------
// Block: 512 threads = 8 waves, LDS 128 KB (1 block/CU). Grid 391 -> 3128 waves, one
// 16-row group each (3125 groups exactly cover 50000 rows).
// Stage: 128 chunks of 1 KB (fragment (ks,n): lane ln -> col n*16+(ln&15), k ks*32+(ln>>4)*8)
// via global_load_lds; ONE barrier total. Then each wave streams its rows from x:
// per ks: 2 x float4 loads (full 128B line coverage) -> v_cvt_pk -> 8 ds_read_b128 B-frags
// -> 8 MFMA. Zero steady-state barriers, zero LDS writes, zero block coupling.

__global__ __launch_bounds__(512, 1) void gemm1_mfma(const float* __restrict__ x,
                                                     const unsigned short* __restrict__ W1t,
                                                     unsigned short* __restrict__ pre1b) {
    __shared__ char lds[131072];   // whole W1t, fragment-chunk order

    const int t = threadIdx.x;
    const int w = t >> 6;            // wave 0..7
    const int l = t & 63;
    const int l15 = l & 15;
    const int lhi = l >> 4;

    // stage: wave w loads chunks w*16 .. w*16+15
#pragma unroll
    for (int j = 0; j < 16; ++j) {
        int c = w * 16 + j;          // wave-uniform chunk id
        int n = c & 7, ks = c >> 3;
        int col = n * 16 + l15;
        int k = ks * 32 + lhi * 8;
        __builtin_amdgcn_global_load_lds(W1t + (size_t)col * N_FEAT + k,
                                         (unsigned short*)(lds + c * 1024), 16, 0, 0);
    }
    __syncthreads();   // the only barrier

    const int g = blockIdx.x * 8 + w;    // 16-row group id
    if (g >= N_NODES / 16) return;       // 3 idle waves in last block

    const float* xr = x + (size_t)(g * 16 + l15) * N_FEAT + lhi * 8;

    f32x4 acc[8];
#pragma unroll
    for (int n = 0; n < 8; ++n) acc[n] = (f32x4){0.f, 0.f, 0.f, 0.f};

#pragma unroll 4
    for (int ks = 0; ks < 16; ++ks) {
        float4 a0 = *(const float4*)(xr + ks * 32);
        float4 a1 = *(const float4*)(xr + ks * 32 + 4);
        union { bf16x8 v; __hip_bfloat162 h[4]; } u;
        u.h[0] = __float22bfloat162_rn(make_float2(a0.x, a0.y));
        u.h[1] = __float22bfloat162_rn(make_float2(a0.z, a0.w));
        u.h[2] = __float22bfloat162_rn(make_float2(a1.x, a1.y));
        u.h[3] = __float22bfloat162_rn(make_float2(a1.z, a1.w));
        const char* bp = lds + (ks * 8) * 1024 + l * 16;
#pragma unroll
        for (int n = 0; n < 8; ++n) {
            bf16x8 bf = *(const bf16x8*)(bp + n * 1024);
            acc[n] = __builtin_amdgcn_mfma_f32_16x16x32_bf16(u.v, bf, acc[n], 0, 0, 0);
        }
    }
    // epilogue: C/D layout col=lane&15, row=(lane>>4)*4+reg
    unsigned short* orow = pre1b + (size_t)(g * 16 + lhi * 4) * HIDDEN + l15;
#pragma unroll
    for (int n = 0; n < 8; ++n)
#pragma unroll
        for (int j = 0; j < 4; ++j)
            orow[(size_t)j * HIDDEN + n * 16] = f2bf(acc[n][j]);
}

// ---------------- SpMM1: hb = bf16(relu(A @ pre1)), one wave per node, 1 uint (2 feats)/lane ----------------

__global__ __launch_bounds__(256) void spmm1_k(const int* __restrict__ rp,
                                               const unsigned long long* __restrict__ ce,
                                               const unsigned* __restrict__ P,
                                               unsigned* __restrict__ hb) {
    const int g = threadIdx.x >> 6;
    const int lane = threadIdx.x & 63;
    const int node = blockIdx.x * 4 + g;
    if (node >= N_NODES) return;
    const int s = rp[node], e = rp[node + 1];
    float2 a0; a0.x = 0.f; a0.y = 0.f;
    float2 a1; a1.x = 0.f; a1.y = 0.f;
    int i = s;
    for (; i + 2 <= e; i += 2) {
        unsigned long long e0 = ce[i], e1 = ce[i + 1];
        int d0 = (int)(unsigned)e0, d1 = (int)(unsigned)e1;
        float v0 = __uint_as_float((unsigned)(e0 >> 32));
        float v1 = __uint_as_float((unsigned)(e1 >> 32));
        unsigned u0 = P[(size_t)d0 * 64 + lane];
        unsigned u1 = P[(size_t)d1 * 64 + lane];
        a0.x += v0 * bflo(u0); a0.y += v0 * bfhi(u0);
        a1.x += v1 * bflo(u1); a1.y += v1 * bfhi(u1);
    }
    if (i < e) {
        unsigned long long e0 = ce[i];
        int d0 = (int)(unsigned)e0;
        float v0 = __uint_as_float((unsigned)(e0 >> 32));
        unsigned u0 = P[(size_t)d0 * 64 + lane];
        a0.x += v0 * bflo(u0); a0.y += v0 * bfhi(u0);
    }
    a0.x += a1.x; a0.y += a1.y;
    a0.x = a0.x > 0.f ? a0.x : 0.f;
    a0.y = a0.y > 0.f ? a0.y : 0.f;
    hb[(size_t)node * 64 + lane] = pack2(a0.x, a0.y);
}

// ---------------- GEMM2: pre2b[50000,32] = bf16(h @ W2) ----------------

__global__ __launch_bounds__(256) void gemm2_k(const unsigned* __restrict__ hb,
                                               const float* __restrict__ W2,
                                               unsigned short* __restrict__ pre2b) {
    __shared__ float hs[32][132];
    __shared__ float w2s[HIDDEN][N_CLASSES];
    const int t = threadIdx.x;
    const int row0 = blockIdx.x * 32;
#pragma unroll
    for (int j = 0; j < 4; ++j) {        // W2: 1024 float4
        int f = j * 256 + t;
        int r = f >> 3;
        int c = (f & 7) << 2;
        *(float4*)&w2s[r][c] = *(const float4*)(W2 + (size_t)r * N_CLASSES + c);
    }
#pragma unroll
    for (int j = 0; j < 2; ++j) {        // h tile: 32 rows x 64 uints = 2048 uints
        int f = j * 256 + t;
        int r = f >> 4;                  // 0..31
        int cu = (f & 15) << 2;          // uint col 0..60 step 4
        int grr = row0 + r;
        if (grr >= N_NODES) grr = N_NODES - 1;
        uint4 u = *(const uint4*)(hb + (size_t)grr * 64 + cu);
        hs[r][2 * cu + 0] = bflo(u.x); hs[r][2 * cu + 1] = bfhi(u.x);
        hs[r][2 * cu + 2] = bflo(u.y); hs[r][2 * cu + 3] = bfhi(u.y);
        hs[r][2 * cu + 4] = bflo(u.z); hs[r][2 * cu + 5] = bfhi(u.z);
        hs[r][2 * cu + 6] = bflo(u.w); hs[r][2 * cu + 7] = bfhi(u.w);
    }
    __syncthreads();
    const int r = t >> 3;
    const int c = (t & 7) << 2;
    float4 acc; acc.x = acc.y = acc.z = acc.w = 0.f;
#pragma unroll 16
    for (int kk = 0; kk < HIDDEN; ++kk) {
        float a = hs[r][kk];
        float4 b = *(const float4*)&w2s[kk][c];
        acc.x += a * b.x; acc.y += a * b.y; acc.z += a * b.z; acc.w += a * b.w;
    }
    int grr = row0 + r;
    if (grr < N_NODES) {
        uint2 o;
        o.x = pack2(acc.x, acc.y);
        o.y = pack2(acc.z, acc.w);
        *(uint2*)&pre2b[(size_t)grr * N_CLASSES + c] = o;
    }
}

// ---------------- SpMM2: out = A @ pre2 ; 16 lanes/edge, 4 edges/iter ----------------

__global__ __launch_bounds__(256) void spmm2_k(const int* __restrict__ rp,
                                               const unsigned long long* __restrict__ ce,
                                               const unsigned* __restrict__ P2,
                                               float* __restrict__ out) {
    const int g = threadIdx.x >> 6;
    const int lane = threadIdx.x & 63;
    const int node = blockIdx.x * 4 + g;
    if (node >= N_NODES) return;
    const int s = rp[node], e = rp[node + 1];
    const int f2 = lane & 15;      // uint index: feats 2*f2, 2*f2+1
    const int par = lane >> 4;     // 0..3
    float ax = 0.f, ay = 0.f;
    for (int i = s + par; i < e; i += 4) {
        unsigned long long ed = ce[i];
        int dst = (int)(unsigned)ed;
        float v = __uint_as_float((unsigned)(ed >> 32));
        unsigned u = P2[(size_t)dst * 16 + f2];
        ax += v * bflo(u);
        ay += v * bfhi(u);
    }
    ax += __shfl_xor(ax, 16); ay += __shfl_xor(ay, 16);
    ax += __shfl_xor(ax, 32); ay += __shfl_xor(ay, 32);
    if (lane < 16) {
        float2 o; o.x = ax; o.y = ay;
        ((float2*)out)[(size_t)node * 16 + f2] = o;
    }
}

// ---------------- launch ----------------

extern "C" void kernel_launch(void* const* d_in, const int* in_sizes, int n_in,
                              void* d_out, int out_size, void* d_ws, size_t ws_size,
                              hipStream_t stream) {
    const float* x    = (const float*)d_in[0];
    const int* esrc   = (const int*)d_in[1];
    const int* edst   = (const int*)d_in[2];
    const float* ev   = (const float*)d_in[3];
    const float* W1   = (const float*)d_in[4];
    const float* W2   = (const float*)d_in[5];
    float* out        = (float*)d_out;

    // workspace layout; pre2b aliases pre1b (pre1b dead after spmm1)
    unsigned short* pre1b = (unsigned short*)d_ws;            // 6,400,000 ushort (12.8 MB)
    unsigned* hb          = (unsigned*)(pre1b + 6400000);     // 3,200,000 uint (12.8 MB)
    unsigned short* pre2b = pre1b;                            // alias
    unsigned long long* csr_ev = (unsigned long long*)(hb + 3200000);   // 800,000 u64 (6.4 MB)
    unsigned long long* tmp    = csr_ev + 800000;             // 196*6144 u64 (9.63 MB)
    int* row_ptr          = (int*)(tmp + (size_t)NBUCK * REG_STRIDE);   // 50,001 (pad 50,048)
    int* gcursor          = row_ptr + 50048;                  // 256
    unsigned short* W1t   = (unsigned short*)(gcursor + 256); // 65,536 ushort

    hipLaunchKernelGGL(w1conv_k,   dim3(256),  dim3(256), 0, stream, W1, W1t, gcursor);
    hipLaunchKernelGGL(bucket1_k,  dim3(391),  dim3(256), 0, stream, esrc, edst, ev, gcursor, tmp);
    hipLaunchKernelGGL(bucket2_k,  dim3(NBUCK),dim3(256), 0, stream, gcursor, tmp, csr_ev, row_ptr);

    hipLaunchKernelGGL(gemm1_mfma, dim3(391),  dim3(512), 0, stream, x, W1t, pre1b);
    hipLaunchKernelGGL(spmm1_k,    dim3(12500),dim3(256), 0, stream, row_ptr, csr_ev, (const unsigned*)pre1b, hb);
    hipLaunchKernelGGL(gemm2_k,    dim3(1563), dim3(256), 0, stream, hb, W2, pre2b);
    hipLaunchKernelGGL(spmm2_k,    dim3(12500),dim3(256), 0, stream, row_ptr, csr_ev, (const unsigned*)pre2b, out);
}

// Round 12
// 148.514 us; speedup vs baseline: 1.3286x; 1.0345x over previous
//
#include <hip/hip_runtime.h>
#include <hip/hip_bf16.h>

#define N_NODES 50000
#define N_EDGES 800000
#define N_FEAT 512
#define HIDDEN 128
#define N_CLASSES 32

#define NBUCK 196        // coarse buckets: src>>8 (256-node regions)
#define REG_STRIDE 6144  // slots per region (mean 4081, sigma 64 -> 30+ sigma headroom)

typedef __attribute__((ext_vector_type(8))) short bf16x8;
typedef __attribute__((ext_vector_type(4))) float f32x4;

// round-to-nearest-even f32 -> bf16 bits (cold paths)
static __device__ __forceinline__ unsigned short f2bf(float f) {
    unsigned u = __float_as_uint(f);
    u += 0x7FFFu + ((u >> 16) & 1u);
    return (unsigned short)(u >> 16);
}
// unpack uint = (bf16_hi<<16)|bf16_lo
static __device__ __forceinline__ float bflo(unsigned u) { return __uint_as_float(u << 16); }
static __device__ __forceinline__ float bfhi(unsigned u) { return __uint_as_float(u & 0xFFFF0000u); }
// HW packed cvt: one v_cvt_pk_bf16_f32 (RNE)
static __device__ __forceinline__ unsigned pack2(float a, float b) {
    union { __hip_bfloat162 h; unsigned u; } c;
    c.h = __float22bfloat162_rn(make_float2(a, b));
    return c.u;
}

// ---------------- CSR build, phase 1: LDS-bucketed coarse scatter ----------------
// record: src(16) | dst(16)<<16 | val_bits<<32

__global__ __launch_bounds__(256) void bucket1_k(const int* __restrict__ src, const int* __restrict__ dst,
                                                 const float* __restrict__ val,
                                                 int* __restrict__ gcursor,
                                                 unsigned long long* __restrict__ tmp) {
    __shared__ int cnt[256];
    __shared__ int lstart[256];
    __shared__ int lcur[256];
    __shared__ int gbase[256];
    __shared__ unsigned long long buf[2048];   // 16 KB
    const int t = threadIdx.x;
    const int e0 = blockIdx.x * 2048;
    const int ne = min(2048, N_EDGES - e0);

    cnt[t] = 0;
    __syncthreads();

    unsigned long long rec[8];
    int rb[8];
#pragma unroll
    for (int j = 0; j < 8; ++j) {
        int p = j * 256 + t;
        rec[j] = 0; rb[j] = -1;
        if (p < ne) {
            int i = e0 + p;
            unsigned s = (unsigned)src[i];
            rec[j] = (unsigned long long)(s | ((unsigned)dst[i] << 16))
                   | ((unsigned long long)__float_as_uint(val[i]) << 32);
            int b = (int)(s >> 8);
            rb[j] = b;
            atomicAdd(&cnt[b], 1);
        }
    }
    __syncthreads();
    const int cv = cnt[t];
    // inclusive scan (Hillis-Steele)
    for (int off = 1; off < 256; off <<= 1) {
        int xv = (t >= off) ? cnt[t - off] : 0;
        __syncthreads();
        cnt[t] += xv;
        __syncthreads();
    }
    lstart[t] = cnt[t] - cv;
    lcur[t]   = cnt[t] - cv;
    if (t < NBUCK) gbase[t] = atomicAdd(&gcursor[t], cv);
    __syncthreads();
    // place records bucket-grouped into LDS
#pragma unroll
    for (int j = 0; j < 8; ++j) {
        if (rb[j] >= 0) {
            int pos = atomicAdd(&lcur[rb[j]], 1);
            buf[pos] = rec[j];
        }
    }
    __syncthreads();
    // burst write-out: consecutive p within a bucket -> consecutive global slots
#pragma unroll
    for (int j = 0; j < 8; ++j) {
        int p = j * 256 + t;
        if (p < ne) {
            unsigned long long r = buf[p];
            int b = (int)((r & 0xFFFFu) >> 8);
            int tgt = gbase[b] + (p - lstart[b]);
            tmp[(size_t)b * REG_STRIDE + tgt] = r;
        }
    }
}

// ---------------- CSR build, phase 2: per-region local sort + row_ptr ----------------

__global__ __launch_bounds__(256) void bucket2_k(const int* __restrict__ gcursor,
                                                 const unsigned long long* __restrict__ tmp,
                                                 unsigned long long* __restrict__ csr_ev,
                                                 int* __restrict__ row_ptr) {
    __shared__ int lcnt[256];
    __shared__ int lcur[256];
    __shared__ int cnts[NBUCK];
    __shared__ int base_s;
    const int b = blockIdx.x;
    const int t = threadIdx.x;
    if (t < NBUCK) cnts[t] = gcursor[t];
    lcnt[t] = 0;
    __syncthreads();
    const int nb = cnts[b];
    if (t == 0) {
        int s = 0;
        for (int r = 0; r < b; ++r) s += cnts[r];
        base_s = s;
    }
    const unsigned long long* reg = tmp + (size_t)b * REG_STRIDE;
    __syncthreads();
    // pass 1: per-node counts (local node = rec & 255, regions are 256-aligned)
    for (int p = t; p < nb; p += 256)
        atomicAdd(&lcnt[(int)(reg[p] & 0xFFu)], 1);
    __syncthreads();
    const int cv = lcnt[t];
    for (int off = 1; off < 256; off <<= 1) {
        int xv = (t >= off) ? lcnt[t - off] : 0;
        __syncthreads();
        lcnt[t] += xv;
        __syncthreads();
    }
    const int abs_start = base_s + lcnt[t] - cv;
    lcur[t] = abs_start;
    int node = b * 256 + t;
    if (node <= N_NODES) row_ptr[node] = abs_start;
    __syncthreads();
    // pass 2: place (L2-hot ~33KB window)
    for (int p = t; p < nb; p += 256) {
        unsigned long long r = reg[p];
        int pos = atomicAdd(&lcur[(int)(r & 0xFFu)], 1);
        csr_ev[pos] = ((r >> 16) & 0xFFFFull) | (r & 0xFFFFFFFF00000000ull);
    }
}

// ---------------- W1 transpose + bf16 (+ gcursor zero): W1[512][128] -> W1t[128][512] ----------------

__global__ __launch_bounds__(256) void w1conv_k(const float* __restrict__ W1,
                                                unsigned short* __restrict__ W1t,
                                                int* __restrict__ gcursor) {
    if (blockIdx.x == 0 && threadIdx.x < NBUCK) gcursor[threadIdx.x] = 0;
    int id = blockIdx.x * 256 + threadIdx.x;   // 65536
    int c = id >> 9;          // 0..127
    int k = id & 511;         // 0..511
    W1t[(size_t)c * N_FEAT + k] = f2bf(W1[(size_t)k * HIDDEN + c]);
}

// ---------------- GEMM1: whole W1t in LDS; balanced per-wave streaming ----------------
// Block: 1024 threads = 16 waves, LDS 128 KB, grid 256 = exactly 1 block/CU (4 waves/SIMD).
// Wave->group map g = w*256 + blockIdx.x: 3125 = 12*256+53 -> EVERY block has 12-13
// active waves (no block-level tail; waves 13..15 idle post-staging).
// Stage: 128 x 1KB fragment chunks via global_load_lds (8 per wave), ONE barrier.
// K-loop: depth-1 reg prefetch of next 2 x float4 -> v_cvt_pk -> 8 ds_read_b128 -> 8 MFMA.

__global__ __launch_bounds__(1024, 1) void gemm1_mfma(const float* __restrict__ x,
                                                      const unsigned short* __restrict__ W1t,
                                                      unsigned short* __restrict__ pre1b) {
    __shared__ char lds[131072];   // whole W1t, fragment-chunk order

    const int t = threadIdx.x;
    const int w = t >> 6;            // wave 0..15
    const int l = t & 63;
    const int l15 = l & 15;
    const int lhi = l >> 4;

    // stage: wave w loads chunks w*8 .. w*8+7
#pragma unroll
    for (int j = 0; j < 8; ++j) {
        int c = w * 8 + j;           // wave-uniform chunk id
        int n = c & 7, ks = c >> 3;
        int col = n * 16 + l15;
        int k = ks * 32 + lhi * 8;
        __builtin_amdgcn_global_load_lds(W1t + (size_t)col * N_FEAT + k,
                                         (unsigned short*)(lds + c * 1024), 16, 0, 0);
    }
    __syncthreads();   // the only barrier

    const int g = w * 256 + blockIdx.x;    // strided 16-row-group id (balanced per block)
    if (g >= N_NODES / 16) return;

    const float* xr = x + (size_t)(g * 16 + l15) * N_FEAT + lhi * 8;

    f32x4 acc[8];
#pragma unroll
    for (int n = 0; n < 8; ++n) acc[n] = (f32x4){0.f, 0.f, 0.f, 0.f};

    float4 a0 = *(const float4*)(xr);
    float4 a1 = *(const float4*)(xr + 4);
#pragma unroll
    for (int ks = 0; ks < 16; ++ks) {
        float4 c0 = a0, c1 = a1;
        if (ks < 15) {                         // depth-1 prefetch: issue before MFMA chain
            a0 = *(const float4*)(xr + (ks + 1) * 32);
            a1 = *(const float4*)(xr + (ks + 1) * 32 + 4);
        }
        union { bf16x8 v; __hip_bfloat162 h[4]; } u;
        u.h[0] = __float22bfloat162_rn(make_float2(c0.x, c0.y));
        u.h[1] = __float22bfloat162_rn(make_float2(c0.z, c0.w));
        u.h[2] = __float22bfloat162_rn(make_float2(c1.x, c1.y));
        u.h[3] = __float22bfloat162_rn(make_float2(c1.z, c1.w));
        const char* bp = lds + (ks * 8) * 1024 + l * 16;
#pragma unroll
        for (int n = 0; n < 8; ++n) {
            bf16x8 bf = *(const bf16x8*)(bp + n * 1024);
            acc[n] = __builtin_amdgcn_mfma_f32_16x16x32_bf16(u.v, bf, acc[n], 0, 0, 0);
        }
    }
    // epilogue: C/D layout col=lane&15, row=(lane>>4)*4+reg
    unsigned short* orow = pre1b + (size_t)(g * 16 + lhi * 4) * HIDDEN + l15;
#pragma unroll
    for (int n = 0; n < 8; ++n)
#pragma unroll
        for (int j = 0; j < 4; ++j)
            orow[(size_t)j * HIDDEN + n * 16] = f2bf(acc[n][j]);
}

// ---------------- SpMM1: hb = bf16(relu(A @ pre1)), one wave per node, 1 uint (2 feats)/lane ----------------

__global__ __launch_bounds__(256) void spmm1_k(const int* __restrict__ rp,
                                               const unsigned long long* __restrict__ ce,
                                               const unsigned* __restrict__ P,
                                               unsigned* __restrict__ hb) {
    const int g = threadIdx.x >> 6;
    const int lane = threadIdx.x & 63;
    const int node = blockIdx.x * 4 + g;
    if (node >= N_NODES) return;
    const int s = rp[node], e = rp[node + 1];
    float2 a0; a0.x = 0.f; a0.y = 0.f;
    float2 a1; a1.x = 0.f; a1.y = 0.f;
    int i = s;
    for (; i + 2 <= e; i += 2) {
        unsigned long long e0 = ce[i], e1 = ce[i + 1];
        int d0 = (int)(unsigned)e0, d1 = (int)(unsigned)e1;
        float v0 = __uint_as_float((unsigned)(e0 >> 32));
        float v1 = __uint_as_float((unsigned)(e1 >> 32));
        unsigned u0 = P[(size_t)d0 * 64 + lane];
        unsigned u1 = P[(size_t)d1 * 64 + lane];
        a0.x += v0 * bflo(u0); a0.y += v0 * bfhi(u0);
        a1.x += v1 * bflo(u1); a1.y += v1 * bfhi(u1);
    }
    if (i < e) {
        unsigned long long e0 = ce[i];
        int d0 = (int)(unsigned)e0;
        float v0 = __uint_as_float((unsigned)(e0 >> 32));
        unsigned u0 = P[(size_t)d0 * 64 + lane];
        a0.x += v0 * bflo(u0); a0.y += v0 * bfhi(u0);
    }
    a0.x += a1.x; a0.y += a1.y;
    a0.x = a0.x > 0.f ? a0.x : 0.f;
    a0.y = a0.y > 0.f ? a0.y : 0.f;
    hb[(size_t)node * 64 + lane] = pack2(a0.x, a0.y);
}

// ---------------- GEMM2: pre2b[50000,32] = bf16(h @ W2) ----------------

__global__ __launch_bounds__(256) void gemm2_k(const unsigned* __restrict__ hb,
                                               const float* __restrict__ W2,
                                               unsigned short* __restrict__ pre2b) {
    __shared__ float hs[32][132];
    __shared__ float w2s[HIDDEN][N_CLASSES];
    const int t = threadIdx.x;
    const int row0 = blockIdx.x * 32;
#pragma unroll
    for (int j = 0; j < 4; ++j) {        // W2: 1024 float4
        int f = j * 256 + t;
        int r = f >> 3;
        int c = (f & 7) << 2;
        *(float4*)&w2s[r][c] = *(const float4*)(W2 + (size_t)r * N_CLASSES + c);
    }
#pragma unroll
    for (int j = 0; j < 2; ++j) {        // h tile: 32 rows x 64 uints = 2048 uints
        int f = j * 256 + t;
        int r = f >> 4;                  // 0..31
        int cu = (f & 15) << 2;          // uint col 0..60 step 4
        int grr = row0 + r;
        if (grr >= N_NODES) grr = N_NODES - 1;
        uint4 u = *(const uint4*)(hb + (size_t)grr * 64 + cu);
        hs[r][2 * cu + 0] = bflo(u.x); hs[r][2 * cu + 1] = bfhi(u.x);
        hs[r][2 * cu + 2] = bflo(u.y); hs[r][2 * cu + 3] = bfhi(u.y);
        hs[r][2 * cu + 4] = bflo(u.z); hs[r][2 * cu + 5] = bfhi(u.z);
        hs[r][2 * cu + 6] = bflo(u.w); hs[r][2 * cu + 7] = bfhi(u.w);
    }
    __syncthreads();
    const int r = t >> 3;
    const int c = (t & 7) << 2;
    float4 acc; acc.x = acc.y = acc.z = acc.w = 0.f;
#pragma unroll 16
    for (int kk = 0; kk < HIDDEN; ++kk) {
        float a = hs[r][kk];
        float4 b = *(const float4*)&w2s[kk][c];
        acc.x += a * b.x; acc.y += a * b.y; acc.z += a * b.z; acc.w += a * b.w;
    }
    int grr = row0 + r;
    if (grr < N_NODES) {
        uint2 o;
        o.x = pack2(acc.x, acc.y);
        o.y = pack2(acc.z, acc.w);
        *(uint2*)&pre2b[(size_t)grr * N_CLASSES + c] = o;
    }
}

// ---------------- SpMM2: out = A @ pre2 ; 16 lanes/edge, 4 edges/iter ----------------

__global__ __launch_bounds__(256) void spmm2_k(const int* __restrict__ rp,
                                               const unsigned long long* __restrict__ ce,
                                               const unsigned* __restrict__ P2,
                                               float* __restrict__ out) {
    const int g = threadIdx.x >> 6;
    const int lane = threadIdx.x & 63;
    const int node = blockIdx.x * 4 + g;
    if (node >= N_NODES) return;
    const int s = rp[node], e = rp[node + 1];
    const int f2 = lane & 15;      // uint index: feats 2*f2, 2*f2+1
    const int par = lane >> 4;     // 0..3
    float ax = 0.f, ay = 0.f;
    for (int i = s + par; i < e; i += 4) {
        unsigned long long ed = ce[i];
        int dst = (int)(unsigned)ed;
        float v = __uint_as_float((unsigned)(ed >> 32));
        unsigned u = P2[(size_t)dst * 16 + f2];
        ax += v * bflo(u);
        ay += v * bfhi(u);
    }
    ax += __shfl_xor(ax, 16); ay += __shfl_xor(ay, 16);
    ax += __shfl_xor(ax, 32); ay += __shfl_xor(ay, 32);
    if (lane < 16) {
        float2 o; o.x = ax; o.y = ay;
        ((float2*)out)[(size_t)node * 16 + f2] = o;
    }
}

// ---------------- launch ----------------

extern "C" void kernel_launch(void* const* d_in, const int* in_sizes, int n_in,
                              void* d_out, int out_size, void* d_ws, size_t ws_size,
                              hipStream_t stream) {
    const float* x    = (const float*)d_in[0];
    const int* esrc   = (const int*)d_in[1];
    const int* edst   = (const int*)d_in[2];
    const float* ev   = (const float*)d_in[3];
    const float* W1   = (const float*)d_in[4];
    const float* W2   = (const float*)d_in[5];
    float* out        = (float*)d_out;

    // workspace layout; pre2b aliases pre1b (pre1b dead after spmm1)
    unsigned short* pre1b = (unsigned short*)d_ws;            // 6,400,000 ushort (12.8 MB)
    unsigned* hb          = (unsigned*)(pre1b + 6400000);     // 3,200,000 uint (12.8 MB)
    unsigned short* pre2b = pre1b;                            // alias
    unsigned long long* csr_ev = (unsigned long long*)(hb + 3200000);   // 800,000 u64 (6.4 MB)
    unsigned long long* tmp    = csr_ev + 800000;             // 196*6144 u64 (9.63 MB)
    int* row_ptr          = (int*)(tmp + (size_t)NBUCK * REG_STRIDE);   // 50,001 (pad 50,048)
    int* gcursor          = row_ptr + 50048;                  // 256
    unsigned short* W1t   = (unsigned short*)(gcursor + 256); // 65,536 ushort

    hipLaunchKernelGGL(w1conv_k,   dim3(256),  dim3(256), 0, stream, W1, W1t, gcursor);
    hipLaunchKernelGGL(bucket1_k,  dim3(391),  dim3(256), 0, stream, esrc, edst, ev, gcursor, tmp);
    hipLaunchKernelGGL(bucket2_k,  dim3(NBUCK),dim3(256), 0, stream, gcursor, tmp, csr_ev, row_ptr);

    hipLaunchKernelGGL(gemm1_mfma, dim3(256),  dim3(1024), 0, stream, x, W1t, pre1b);
    hipLaunchKernelGGL(spmm1_k,    dim3(12500),dim3(256), 0, stream, row_ptr, csr_ev, (const unsigned*)pre1b, hb);
    hipLaunchKernelGGL(gemm2_k,    dim3(1563), dim3(256), 0, stream, hb, W2, pre2b);
    hipLaunchKernelGGL(spmm2_k,    dim3(12500),dim3(256), 0, stream, row_ptr, csr_ev, (const unsigned*)pre2b, out);
}

// Round 13
// 132.573 us; speedup vs baseline: 1.4884x; 1.1202x over previous
//
#include <hip/hip_runtime.h>
#include <hip/hip_bf16.h>

#define N_NODES 50000
#define N_EDGES 800000
#define N_FEAT 512
#define HIDDEN 128
#define N_CLASSES 32

#define NBUCK 196        // coarse buckets: src>>8 (256-node regions)
#define REG_STRIDE 6144  // slots per region (mean 4081, sigma 64 -> 30+ sigma headroom)

typedef __attribute__((ext_vector_type(8))) short bf16x8;
typedef __attribute__((ext_vector_type(4))) float f32x4;

// round-to-nearest-even f32 -> bf16 bits (cold paths)
static __device__ __forceinline__ unsigned short f2bf(float f) {
    unsigned u = __float_as_uint(f);
    u += 0x7FFFu + ((u >> 16) & 1u);
    return (unsigned short)(u >> 16);
}
// unpack uint = (bf16_hi<<16)|bf16_lo
static __device__ __forceinline__ float bflo(unsigned u) { return __uint_as_float(u << 16); }
static __device__ __forceinline__ float bfhi(unsigned u) { return __uint_as_float(u & 0xFFFF0000u); }
// HW packed cvt: one v_cvt_pk_bf16_f32 (RNE)
static __device__ __forceinline__ unsigned pack2(float a, float b) {
    union { __hip_bfloat162 h; unsigned u; } c;
    c.h = __float22bfloat162_rn(make_float2(a, b));
    return c.u;
}

// ---------------- CSR build, phase 1: LDS-bucketed coarse scatter ----------------
// record: src(16) | dst(16)<<16 | val_bits<<32

__global__ __launch_bounds__(256) void bucket1_k(const int* __restrict__ src, const int* __restrict__ dst,
                                                 const float* __restrict__ val,
                                                 int* __restrict__ gcursor,
                                                 unsigned long long* __restrict__ tmp) {
    __shared__ int cnt[256];
    __shared__ int lstart[256];
    __shared__ int lcur[256];
    __shared__ int gbase[256];
    __shared__ unsigned long long buf[2048];   // 16 KB
    const int t = threadIdx.x;
    const int e0 = blockIdx.x * 2048;
    const int ne = min(2048, N_EDGES - e0);

    cnt[t] = 0;
    __syncthreads();

    unsigned long long rec[8];
    int rb[8];
#pragma unroll
    for (int j = 0; j < 8; ++j) {
        int p = j * 256 + t;
        rec[j] = 0; rb[j] = -1;
        if (p < ne) {
            int i = e0 + p;
            unsigned s = (unsigned)src[i];
            rec[j] = (unsigned long long)(s | ((unsigned)dst[i] << 16))
                   | ((unsigned long long)__float_as_uint(val[i]) << 32);
            int b = (int)(s >> 8);
            rb[j] = b;
            atomicAdd(&cnt[b], 1);
        }
    }
    __syncthreads();
    const int cv = cnt[t];
    // inclusive scan (Hillis-Steele)
    for (int off = 1; off < 256; off <<= 1) {
        int xv = (t >= off) ? cnt[t - off] : 0;
        __syncthreads();
        cnt[t] += xv;
        __syncthreads();
    }
    lstart[t] = cnt[t] - cv;
    lcur[t]   = cnt[t] - cv;
    if (t < NBUCK) gbase[t] = atomicAdd(&gcursor[t], cv);
    __syncthreads();
    // place records bucket-grouped into LDS
#pragma unroll
    for (int j = 0; j < 8; ++j) {
        if (rb[j] >= 0) {
            int pos = atomicAdd(&lcur[rb[j]], 1);
            buf[pos] = rec[j];
        }
    }
    __syncthreads();
    // burst write-out: consecutive p within a bucket -> consecutive global slots
#pragma unroll
    for (int j = 0; j < 8; ++j) {
        int p = j * 256 + t;
        if (p < ne) {
            unsigned long long r = buf[p];
            int b = (int)((r & 0xFFFFu) >> 8);
            int tgt = gbase[b] + (p - lstart[b]);
            tmp[(size_t)b * REG_STRIDE + tgt] = r;
        }
    }
}

// ---------------- CSR build, phase 2: per-region local sort + row_ptr ----------------

__global__ __launch_bounds__(256) void bucket2_k(const int* __restrict__ gcursor,
                                                 const unsigned long long* __restrict__ tmp,
                                                 unsigned long long* __restrict__ csr_ev,
                                                 int* __restrict__ row_ptr) {
    __shared__ int lcnt[256];
    __shared__ int lcur[256];
    __shared__ int cnts[NBUCK];
    __shared__ int base_s;
    const int b = blockIdx.x;
    const int t = threadIdx.x;
    if (t < NBUCK) cnts[t] = gcursor[t];
    lcnt[t] = 0;
    __syncthreads();
    const int nb = cnts[b];
    if (t == 0) {
        int s = 0;
        for (int r = 0; r < b; ++r) s += cnts[r];
        base_s = s;
    }
    const unsigned long long* reg = tmp + (size_t)b * REG_STRIDE;
    __syncthreads();
    // pass 1: per-node counts (local node = rec & 255, regions are 256-aligned)
    for (int p = t; p < nb; p += 256)
        atomicAdd(&lcnt[(int)(reg[p] & 0xFFu)], 1);
    __syncthreads();
    const int cv = lcnt[t];
    for (int off = 1; off < 256; off <<= 1) {
        int xv = (t >= off) ? lcnt[t - off] : 0;
        __syncthreads();
        lcnt[t] += xv;
        __syncthreads();
    }
    const int abs_start = base_s + lcnt[t] - cv;
    lcur[t] = abs_start;
    int node = b * 256 + t;
    if (node <= N_NODES) row_ptr[node] = abs_start;
    __syncthreads();
    // pass 2: place (L2-hot ~33KB window)
    for (int p = t; p < nb; p += 256) {
        unsigned long long r = reg[p];
        int pos = atomicAdd(&lcur[(int)(r & 0xFFu)], 1);
        csr_ev[pos] = ((r >> 16) & 0xFFFFull) | (r & 0xFFFFFFFF00000000ull);
    }
}

// ---------------- W1 transpose + bf16 (+ gcursor zero): W1[512][128] -> W1t[128][512] ----------------

__global__ __launch_bounds__(256) void w1conv_k(const float* __restrict__ W1,
                                                unsigned short* __restrict__ W1t,
                                                int* __restrict__ gcursor) {
    if (blockIdx.x == 0 && threadIdx.x < NBUCK) gcursor[threadIdx.x] = 0;
    int id = blockIdx.x * 256 + threadIdx.x;   // 65536
    int c = id >> 9;          // 0..127
    int k = id & 511;         // 0..511
    W1t[(size_t)c * N_FEAT + k] = f2bf(W1[(size_t)k * HIDDEN + c]);
}

// ---------------- GEMM1: whole W1t in LDS; balanced per-wave streaming, depth-3 prefetch ----------------
// Block: 1024 threads = 16 waves, LDS 128 KB, grid 256 = exactly 1 block/CU (4 waves/SIMD).
// Wave->group map g = w*256 + blockIdx.x (balanced: every block 12-13 active waves).
// Stage: 128 x 1KB fragment chunks via global_load_lds (8 per wave), ONE barrier.
// K-loop (fully unrolled, static rolling indices): depth-3 reg prefetch -> cvt_pk ->
// setprio(1) 8x{ds_read_b128 + MFMA} setprio(0).

__global__ __launch_bounds__(1024, 1) void gemm1_mfma(const float* __restrict__ x,
                                                      const unsigned short* __restrict__ W1t,
                                                      unsigned short* __restrict__ pre1b) {
    __shared__ char lds[131072];   // whole W1t, fragment-chunk order

    const int t = threadIdx.x;
    const int w = t >> 6;            // wave 0..15
    const int l = t & 63;
    const int l15 = l & 15;
    const int lhi = l >> 4;

    // stage: wave w loads chunks w*8 .. w*8+7
#pragma unroll
    for (int j = 0; j < 8; ++j) {
        int c = w * 8 + j;           // wave-uniform chunk id
        int n = c & 7, ks = c >> 3;
        int col = n * 16 + l15;
        int k = ks * 32 + lhi * 8;
        __builtin_amdgcn_global_load_lds(W1t + (size_t)col * N_FEAT + k,
                                         (unsigned short*)(lds + c * 1024), 16, 0, 0);
    }
    __syncthreads();   // the only barrier

    const int g = w * 256 + blockIdx.x;    // strided 16-row-group id (balanced per block)
    if (g >= N_NODES / 16) return;

    const float* xr = x + (size_t)(g * 16 + l15) * N_FEAT + lhi * 8;

    f32x4 acc[8];
#pragma unroll
    for (int n = 0; n < 8; ++n) acc[n] = (f32x4){0.f, 0.f, 0.f, 0.f};

    // depth-3 rolling prefetch pipeline (static indices after full unroll)
    float4 qa[3], qb[3];
#pragma unroll
    for (int j = 0; j < 3; ++j) {
        qa[j] = *(const float4*)(xr + j * 32);
        qb[j] = *(const float4*)(xr + j * 32 + 4);
    }
#pragma unroll
    for (int ks = 0; ks < 16; ++ks) {
        float4 c0 = qa[ks % 3], c1 = qb[ks % 3];
        if (ks + 3 < 16) {
            qa[ks % 3] = *(const float4*)(xr + (ks + 3) * 32);
            qb[ks % 3] = *(const float4*)(xr + (ks + 3) * 32 + 4);
        }
        union { bf16x8 v; __hip_bfloat162 h[4]; } u;
        u.h[0] = __float22bfloat162_rn(make_float2(c0.x, c0.y));
        u.h[1] = __float22bfloat162_rn(make_float2(c0.z, c0.w));
        u.h[2] = __float22bfloat162_rn(make_float2(c1.x, c1.y));
        u.h[3] = __float22bfloat162_rn(make_float2(c1.z, c1.w));
        const char* bp = lds + (ks * 8) * 1024 + l * 16;
        __builtin_amdgcn_s_setprio(1);
#pragma unroll
        for (int n = 0; n < 8; ++n) {
            bf16x8 bf = *(const bf16x8*)(bp + n * 1024);
            acc[n] = __builtin_amdgcn_mfma_f32_16x16x32_bf16(u.v, bf, acc[n], 0, 0, 0);
        }
        __builtin_amdgcn_s_setprio(0);
    }
    // epilogue: C/D layout col=lane&15, row=(lane>>4)*4+reg
    unsigned short* orow = pre1b + (size_t)(g * 16 + lhi * 4) * HIDDEN + l15;
#pragma unroll
    for (int n = 0; n < 8; ++n)
#pragma unroll
        for (int j = 0; j < 4; ++j)
            orow[(size_t)j * HIDDEN + n * 16] = f2bf(acc[n][j]);
}

// ---------------- SpMM1: hb = bf16(relu(A @ pre1)), one wave per node, 4-edge unroll ----------------

__global__ __launch_bounds__(256) void spmm1_k(const int* __restrict__ rp,
                                               const unsigned long long* __restrict__ ce,
                                               const unsigned* __restrict__ P,
                                               unsigned* __restrict__ hb) {
    const int g = threadIdx.x >> 6;
    const int lane = threadIdx.x & 63;
    const int node = blockIdx.x * 4 + g;
    if (node >= N_NODES) return;
    const int s = rp[node], e = rp[node + 1];
    float2 a0, a1, a2, a3;
    a0.x = a0.y = a1.x = a1.y = 0.f;
    a2.x = a2.y = a3.x = a3.y = 0.f;
    int i = s;
    for (; i + 4 <= e; i += 4) {
        unsigned long long e0 = ce[i],     e1 = ce[i + 1];
        unsigned long long e2 = ce[i + 2], e3 = ce[i + 3];
        unsigned u0 = P[(size_t)(unsigned)e0 * 64 + lane];
        unsigned u1 = P[(size_t)(unsigned)e1 * 64 + lane];
        unsigned u2 = P[(size_t)(unsigned)e2 * 64 + lane];
        unsigned u3 = P[(size_t)(unsigned)e3 * 64 + lane];
        float v0 = __uint_as_float((unsigned)(e0 >> 32));
        float v1 = __uint_as_float((unsigned)(e1 >> 32));
        float v2 = __uint_as_float((unsigned)(e2 >> 32));
        float v3 = __uint_as_float((unsigned)(e3 >> 32));
        a0.x += v0 * bflo(u0); a0.y += v0 * bfhi(u0);
        a1.x += v1 * bflo(u1); a1.y += v1 * bfhi(u1);
        a2.x += v2 * bflo(u2); a2.y += v2 * bfhi(u2);
        a3.x += v3 * bflo(u3); a3.y += v3 * bfhi(u3);
    }
    for (; i < e; ++i) {
        unsigned long long e0 = ce[i];
        unsigned u0 = P[(size_t)(unsigned)e0 * 64 + lane];
        float v0 = __uint_as_float((unsigned)(e0 >> 32));
        a0.x += v0 * bflo(u0); a0.y += v0 * bfhi(u0);
    }
    a0.x += a1.x + a2.x + a3.x;
    a0.y += a1.y + a2.y + a3.y;
    a0.x = a0.x > 0.f ? a0.x : 0.f;
    a0.y = a0.y > 0.f ? a0.y : 0.f;
    hb[(size_t)node * 64 + lane] = pack2(a0.x, a0.y);
}

// ---------------- GEMM2: pre2b[50000,32] = bf16(h @ W2) ----------------

__global__ __launch_bounds__(256) void gemm2_k(const unsigned* __restrict__ hb,
                                               const float* __restrict__ W2,
                                               unsigned short* __restrict__ pre2b) {
    __shared__ float hs[32][132];
    __shared__ float w2s[HIDDEN][N_CLASSES];
    const int t = threadIdx.x;
    const int row0 = blockIdx.x * 32;
#pragma unroll
    for (int j = 0; j < 4; ++j) {        // W2: 1024 float4
        int f = j * 256 + t;
        int r = f >> 3;
        int c = (f & 7) << 2;
        *(float4*)&w2s[r][c] = *(const float4*)(W2 + (size_t)r * N_CLASSES + c);
    }
#pragma unroll
    for (int j = 0; j < 2; ++j) {        // h tile: 32 rows x 64 uints = 2048 uints
        int f = j * 256 + t;
        int r = f >> 4;                  // 0..31
        int cu = (f & 15) << 2;          // uint col 0..60 step 4
        int grr = row0 + r;
        if (grr >= N_NODES) grr = N_NODES - 1;
        uint4 u = *(const uint4*)(hb + (size_t)grr * 64 + cu);
        hs[r][2 * cu + 0] = bflo(u.x); hs[r][2 * cu + 1] = bfhi(u.x);
        hs[r][2 * cu + 2] = bflo(u.y); hs[r][2 * cu + 3] = bfhi(u.y);
        hs[r][2 * cu + 4] = bflo(u.z); hs[r][2 * cu + 5] = bfhi(u.z);
        hs[r][2 * cu + 6] = bflo(u.w); hs[r][2 * cu + 7] = bfhi(u.w);
    }
    __syncthreads();
    const int r = t >> 3;
    const int c = (t & 7) << 2;
    float4 acc; acc.x = acc.y = acc.z = acc.w = 0.f;
#pragma unroll 16
    for (int kk = 0; kk < HIDDEN; ++kk) {
        float a = hs[r][kk];
        float4 b = *(const float4*)&w2s[kk][c];
        acc.x += a * b.x; acc.y += a * b.y; acc.z += a * b.z; acc.w += a * b.w;
    }
    int grr = row0 + r;
    if (grr < N_NODES) {
        uint2 o;
        o.x = pack2(acc.x, acc.y);
        o.y = pack2(acc.z, acc.w);
        *(uint2*)&pre2b[(size_t)grr * N_CLASSES + c] = o;
    }
}

// ---------------- SpMM2: out = A @ pre2 ; 16 lanes/edge, 2-deep unroll (8 edges in flight) ----------------

__global__ __launch_bounds__(256) void spmm2_k(const int* __restrict__ rp,
                                               const unsigned long long* __restrict__ ce,
                                               const unsigned* __restrict__ P2,
                                               float* __restrict__ out) {
    const int g = threadIdx.x >> 6;
    const int lane = threadIdx.x & 63;
    const int node = blockIdx.x * 4 + g;
    if (node >= N_NODES) return;
    const int s = rp[node], e = rp[node + 1];
    const int f2 = lane & 15;      // uint index: feats 2*f2, 2*f2+1
    const int par = lane >> 4;     // 0..3
    float ax0 = 0.f, ay0 = 0.f, ax1 = 0.f, ay1 = 0.f;
    int i = s + par;
    for (; i + 4 < e; i += 8) {
        unsigned long long e0 = ce[i], e1 = ce[i + 4];
        unsigned u0 = P2[(size_t)(unsigned)e0 * 16 + f2];
        unsigned u1 = P2[(size_t)(unsigned)e1 * 16 + f2];
        float v0 = __uint_as_float((unsigned)(e0 >> 32));
        float v1 = __uint_as_float((unsigned)(e1 >> 32));
        ax0 += v0 * bflo(u0); ay0 += v0 * bfhi(u0);
        ax1 += v1 * bflo(u1); ay1 += v1 * bfhi(u1);
    }
    if (i < e) {
        unsigned long long e0 = ce[i];
        unsigned u0 = P2[(size_t)(unsigned)e0 * 16 + f2];
        float v0 = __uint_as_float((unsigned)(e0 >> 32));
        ax0 += v0 * bflo(u0); ay0 += v0 * bfhi(u0);
    }
    float ax = ax0 + ax1, ay = ay0 + ay1;
    ax += __shfl_xor(ax, 16); ay += __shfl_xor(ay, 16);
    ax += __shfl_xor(ax, 32); ay += __shfl_xor(ay, 32);
    if (lane < 16) {
        float2 o; o.x = ax; o.y = ay;
        ((float2*)out)[(size_t)node * 16 + f2] = o;
    }
}

// ---------------- launch ----------------

extern "C" void kernel_launch(void* const* d_in, const int* in_sizes, int n_in,
                              void* d_out, int out_size, void* d_ws, size_t ws_size,
                              hipStream_t stream) {
    const float* x    = (const float*)d_in[0];
    const int* esrc   = (const int*)d_in[1];
    const int* edst   = (const int*)d_in[2];
    const float* ev   = (const float*)d_in[3];
    const float* W1   = (const float*)d_in[4];
    const float* W2   = (const float*)d_in[5];
    float* out        = (float*)d_out;

    // workspace layout; pre2b aliases pre1b (pre1b dead after spmm1)
    unsigned short* pre1b = (unsigned short*)d_ws;            // 6,400,000 ushort (12.8 MB)
    unsigned* hb          = (unsigned*)(pre1b + 6400000);     // 3,200,000 uint (12.8 MB)
    unsigned short* pre2b = pre1b;                            // alias
    unsigned long long* csr_ev = (unsigned long long*)(hb + 3200000);   // 800,000 u64 (6.4 MB)
    unsigned long long* tmp    = csr_ev + 800000;             // 196*6144 u64 (9.63 MB)
    int* row_ptr          = (int*)(tmp + (size_t)NBUCK * REG_STRIDE);   // 50,001 (pad 50,048)
    int* gcursor          = row_ptr + 50048;                  // 256
    unsigned short* W1t   = (unsigned short*)(gcursor + 256); // 65,536 ushort

    hipLaunchKernelGGL(w1conv_k,   dim3(256),  dim3(256), 0, stream, W1, W1t, gcursor);
    hipLaunchKernelGGL(bucket1_k,  dim3(391),  dim3(256), 0, stream, esrc, edst, ev, gcursor, tmp);
    hipLaunchKernelGGL(bucket2_k,  dim3(NBUCK),dim3(256), 0, stream, gcursor, tmp, csr_ev, row_ptr);

    hipLaunchKernelGGL(gemm1_mfma, dim3(256),  dim3(1024), 0, stream, x, W1t, pre1b);
    hipLaunchKernelGGL(spmm1_k,    dim3(12500),dim3(256), 0, stream, row_ptr, csr_ev, (const unsigned*)pre1b, hb);
    hipLaunchKernelGGL(gemm2_k,    dim3(1563), dim3(256), 0, stream, hb, W2, pre2b);
    hipLaunchKernelGGL(spmm2_k,    dim3(12500),dim3(256), 0, stream, row_ptr, csr_ev, (const unsigned*)pre2b, out);
}

// Round 14
// 131.789 us; speedup vs baseline: 1.4972x; 1.0059x over previous
//
#include <hip/hip_runtime.h>
#include <hip/hip_bf16.h>

#define N_NODES 50000
#define N_EDGES 800000
#define N_FEAT 512
#define HIDDEN 128
#define N_CLASSES 32

#define NBUCK 196        // coarse buckets: src>>8 (256-node regions)
#define REG_STRIDE 6144  // slots per region (mean 4081, sigma 64 -> 30+ sigma headroom)
#define NCHUNK 7         // dst-chunks: dst>>13 -> 0..6 (8192-node / 2MB L2 windows)

typedef __attribute__((ext_vector_type(8))) short bf16x8;
typedef __attribute__((ext_vector_type(4))) float f32x4;

// round-to-nearest-even f32 -> bf16 bits (cold paths)
static __device__ __forceinline__ unsigned short f2bf(float f) {
    unsigned u = __float_as_uint(f);
    u += 0x7FFFu + ((u >> 16) & 1u);
    return (unsigned short)(u >> 16);
}
// unpack uint = (bf16_hi<<16)|bf16_lo
static __device__ __forceinline__ float bflo(unsigned u) { return __uint_as_float(u << 16); }
static __device__ __forceinline__ float bfhi(unsigned u) { return __uint_as_float(u & 0xFFFF0000u); }
// HW packed cvt: one v_cvt_pk_bf16_f32 (RNE)
static __device__ __forceinline__ unsigned pack2(float a, float b) {
    union { __hip_bfloat162 h; unsigned u; } c;
    c.h = __float22bfloat162_rn(make_float2(a, b));
    return c.u;
}

// ---------------- CSR build, phase 1: LDS-bucketed coarse scatter ----------------
// record: src(16) | dst(16)<<16 | val_bits<<32

__global__ __launch_bounds__(256) void bucket1_k(const int* __restrict__ src, const int* __restrict__ dst,
                                                 const float* __restrict__ val,
                                                 int* __restrict__ gcursor,
                                                 unsigned long long* __restrict__ tmp) {
    __shared__ int cnt[256];
    __shared__ int lstart[256];
    __shared__ int lcur[256];
    __shared__ int gbase[256];
    __shared__ unsigned long long buf[2048];   // 16 KB
    const int t = threadIdx.x;
    const int e0 = blockIdx.x * 2048;
    const int ne = min(2048, N_EDGES - e0);

    cnt[t] = 0;
    __syncthreads();

    unsigned long long rec[8];
    int rb[8];
#pragma unroll
    for (int j = 0; j < 8; ++j) {
        int p = j * 256 + t;
        rec[j] = 0; rb[j] = -1;
        if (p < ne) {
            int i = e0 + p;
            unsigned s = (unsigned)src[i];
            rec[j] = (unsigned long long)(s | ((unsigned)dst[i] << 16))
                   | ((unsigned long long)__float_as_uint(val[i]) << 32);
            int b = (int)(s >> 8);
            rb[j] = b;
            atomicAdd(&cnt[b], 1);
        }
    }
    __syncthreads();
    const int cv = cnt[t];
    // inclusive scan (Hillis-Steele)
    for (int off = 1; off < 256; off <<= 1) {
        int xv = (t >= off) ? cnt[t - off] : 0;
        __syncthreads();
        cnt[t] += xv;
        __syncthreads();
    }
    lstart[t] = cnt[t] - cv;
    lcur[t]   = cnt[t] - cv;
    if (t < NBUCK) gbase[t] = atomicAdd(&gcursor[t], cv);
    __syncthreads();
    // place records bucket-grouped into LDS
#pragma unroll
    for (int j = 0; j < 8; ++j) {
        if (rb[j] >= 0) {
            int pos = atomicAdd(&lcur[rb[j]], 1);
            buf[pos] = rec[j];
        }
    }
    __syncthreads();
    // burst write-out: consecutive p within a bucket -> consecutive global slots
#pragma unroll
    for (int j = 0; j < 8; ++j) {
        int p = j * 256 + t;
        if (p < ne) {
            unsigned long long r = buf[p];
            int b = (int)((r & 0xFFFFu) >> 8);
            int tgt = gbase[b] + (p - lstart[b]);
            tmp[(size_t)b * REG_STRIDE + tgt] = r;
        }
    }
}

// ---------------- CSR build, phase 2: per-region sort by (node, dst-chunk) + row_ptr ----------------
// dst-chunk ordering within each row gives spmm gathers GPU-wide temporal L2 locality
// (2 MB windows sweep in rough phase across all waves).

__global__ __launch_bounds__(256) void bucket2_k(const int* __restrict__ gcursor,
                                                 const unsigned long long* __restrict__ tmp,
                                                 unsigned long long* __restrict__ csr_ev,
                                                 int* __restrict__ row_ptr) {
    __shared__ int lcnt[256 * NCHUNK];   // [node][chunk]
    __shared__ int lcur[256 * NCHUNK];
    __shared__ int rowsum[256];
    __shared__ int cnts[NBUCK];
    __shared__ int base_s;
    const int b = blockIdx.x;
    const int t = threadIdx.x;
    if (t < NBUCK) cnts[t] = gcursor[t];
    for (int j = t; j < 256 * NCHUNK; j += 256) lcnt[j] = 0;
    __syncthreads();
    const int nb = cnts[b];
    if (t == 0) {
        int s = 0;
        for (int r = 0; r < b; ++r) s += cnts[r];
        base_s = s;
    }
    const unsigned long long* reg = tmp + (size_t)b * REG_STRIDE;
    __syncthreads();
    // pass 1: per-(node,chunk) counts (local node = rec & 255; chunk = dst>>13)
    for (int p = t; p < nb; p += 256) {
        unsigned long long r = reg[p];
        int n = (int)(r & 0xFFu);
        int ch = (int)(((r >> 16) & 0xFFFFu) >> 13);
        atomicAdd(&lcnt[n * NCHUNK + ch], 1);
    }
    __syncthreads();
    // two-level scan: per-thread 7-seq sum, Hillis-Steele over row sums
    int rs = 0;
#pragma unroll
    for (int c = 0; c < NCHUNK; ++c) rs += lcnt[t * NCHUNK + c];
    rowsum[t] = rs;
    __syncthreads();
    for (int off = 1; off < 256; off <<= 1) {
        int xv = (t >= off) ? rowsum[t - off] : 0;
        __syncthreads();
        rowsum[t] += xv;
        __syncthreads();
    }
    const int start = base_s + rowsum[t] - rs;   // exclusive row start
    int o = start;
#pragma unroll
    for (int c = 0; c < NCHUNK; ++c) { lcur[t * NCHUNK + c] = o; o += lcnt[t * NCHUNK + c]; }
    int node = b * 256 + t;
    if (node <= N_NODES) row_ptr[node] = start;
    __syncthreads();
    // pass 2: place in (node, chunk) order (L2-hot window)
    for (int p = t; p < nb; p += 256) {
        unsigned long long r = reg[p];
        int n = (int)(r & 0xFFu);
        int ch = (int)(((r >> 16) & 0xFFFFu) >> 13);
        int pos = atomicAdd(&lcur[n * NCHUNK + ch], 1);
        csr_ev[pos] = ((r >> 16) & 0xFFFFull) | (r & 0xFFFFFFFF00000000ull);
    }
}

// ---------------- W1 transpose + bf16 (+ gcursor zero): W1[512][128] -> W1t[128][512] ----------------

__global__ __launch_bounds__(256) void w1conv_k(const float* __restrict__ W1,
                                                unsigned short* __restrict__ W1t,
                                                int* __restrict__ gcursor) {
    if (blockIdx.x == 0 && threadIdx.x < NBUCK) gcursor[threadIdx.x] = 0;
    int id = blockIdx.x * 256 + threadIdx.x;   // 65536
    int c = id >> 9;          // 0..127
    int k = id & 511;         // 0..511
    W1t[(size_t)c * N_FEAT + k] = f2bf(W1[(size_t)k * HIDDEN + c]);
}

// ---------------- GEMM1: whole W1t in LDS; balanced per-wave streaming, depth-3 prefetch ----------------
// Block: 1024 threads = 16 waves, LDS 128 KB, grid 256 = exactly 1 block/CU (4 waves/SIMD).
// Wave->group map g = w*256 + blockIdx.x (balanced: every block 12-13 active waves).
// Stage: 128 x 1KB fragment chunks via global_load_lds (8 per wave), ONE barrier.
// K-loop (fully unrolled, static rolling indices): depth-3 reg prefetch -> cvt_pk ->
// setprio(1) 8x{ds_read_b128 + MFMA} setprio(0).

__global__ __launch_bounds__(1024, 1) void gemm1_mfma(const float* __restrict__ x,
                                                      const unsigned short* __restrict__ W1t,
                                                      unsigned short* __restrict__ pre1b) {
    __shared__ char lds[131072];   // whole W1t, fragment-chunk order

    const int t = threadIdx.x;
    const int w = t >> 6;            // wave 0..15
    const int l = t & 63;
    const int l15 = l & 15;
    const int lhi = l >> 4;

    // stage: wave w loads chunks w*8 .. w*8+7
#pragma unroll
    for (int j = 0; j < 8; ++j) {
        int c = w * 8 + j;           // wave-uniform chunk id
        int n = c & 7, ks = c >> 3;
        int col = n * 16 + l15;
        int k = ks * 32 + lhi * 8;
        __builtin_amdgcn_global_load_lds(W1t + (size_t)col * N_FEAT + k,
                                         (unsigned short*)(lds + c * 1024), 16, 0, 0);
    }
    __syncthreads();   // the only barrier

    const int g = w * 256 + blockIdx.x;    // strided 16-row-group id (balanced per block)
    if (g >= N_NODES / 16) return;

    const float* xr = x + (size_t)(g * 16 + l15) * N_FEAT + lhi * 8;

    f32x4 acc[8];
#pragma unroll
    for (int n = 0; n < 8; ++n) acc[n] = (f32x4){0.f, 0.f, 0.f, 0.f};

    // depth-3 rolling prefetch pipeline (static indices after full unroll)
    float4 qa[3], qb[3];
#pragma unroll
    for (int j = 0; j < 3; ++j) {
        qa[j] = *(const float4*)(xr + j * 32);
        qb[j] = *(const float4*)(xr + j * 32 + 4);
    }
#pragma unroll
    for (int ks = 0; ks < 16; ++ks) {
        float4 c0 = qa[ks % 3], c1 = qb[ks % 3];
        if (ks + 3 < 16) {
            qa[ks % 3] = *(const float4*)(xr + (ks + 3) * 32);
            qb[ks % 3] = *(const float4*)(xr + (ks + 3) * 32 + 4);
        }
        union { bf16x8 v; __hip_bfloat162 h[4]; } u;
        u.h[0] = __float22bfloat162_rn(make_float2(c0.x, c0.y));
        u.h[1] = __float22bfloat162_rn(make_float2(c0.z, c0.w));
        u.h[2] = __float22bfloat162_rn(make_float2(c1.x, c1.y));
        u.h[3] = __float22bfloat162_rn(make_float2(c1.z, c1.w));
        const char* bp = lds + (ks * 8) * 1024 + l * 16;
        __builtin_amdgcn_s_setprio(1);
#pragma unroll
        for (int n = 0; n < 8; ++n) {
            bf16x8 bf = *(const bf16x8*)(bp + n * 1024);
            acc[n] = __builtin_amdgcn_mfma_f32_16x16x32_bf16(u.v, bf, acc[n], 0, 0, 0);
        }
        __builtin_amdgcn_s_setprio(0);
    }
    // epilogue: C/D layout col=lane&15, row=(lane>>4)*4+reg
    unsigned short* orow = pre1b + (size_t)(g * 16 + lhi * 4) * HIDDEN + l15;
#pragma unroll
    for (int n = 0; n < 8; ++n)
#pragma unroll
        for (int j = 0; j < 4; ++j)
            orow[(size_t)j * HIDDEN + n * 16] = f2bf(acc[n][j]);
}

// ---------------- SpMM1: hb = bf16(relu(A @ pre1)), one wave per node, 4-edge unroll ----------------

__global__ __launch_bounds__(256) void spmm1_k(const int* __restrict__ rp,
                                               const unsigned long long* __restrict__ ce,
                                               const unsigned* __restrict__ P,
                                               unsigned* __restrict__ hb) {
    const int g = threadIdx.x >> 6;
    const int lane = threadIdx.x & 63;
    const int node = blockIdx.x * 4 + g;
    if (node >= N_NODES) return;
    const int s = rp[node], e = rp[node + 1];
    float2 a0, a1, a2, a3;
    a0.x = a0.y = a1.x = a1.y = 0.f;
    a2.x = a2.y = a3.x = a3.y = 0.f;
    int i = s;
    for (; i + 4 <= e; i += 4) {
        unsigned long long e0 = ce[i],     e1 = ce[i + 1];
        unsigned long long e2 = ce[i + 2], e3 = ce[i + 3];
        unsigned u0 = P[(size_t)(unsigned)e0 * 64 + lane];
        unsigned u1 = P[(size_t)(unsigned)e1 * 64 + lane];
        unsigned u2 = P[(size_t)(unsigned)e2 * 64 + lane];
        unsigned u3 = P[(size_t)(unsigned)e3 * 64 + lane];
        float v0 = __uint_as_float((unsigned)(e0 >> 32));
        float v1 = __uint_as_float((unsigned)(e1 >> 32));
        float v2 = __uint_as_float((unsigned)(e2 >> 32));
        float v3 = __uint_as_float((unsigned)(e3 >> 32));
        a0.x += v0 * bflo(u0); a0.y += v0 * bfhi(u0);
        a1.x += v1 * bflo(u1); a1.y += v1 * bfhi(u1);
        a2.x += v2 * bflo(u2); a2.y += v2 * bfhi(u2);
        a3.x += v3 * bflo(u3); a3.y += v3 * bfhi(u3);
    }
    for (; i < e; ++i) {
        unsigned long long e0 = ce[i];
        unsigned u0 = P[(size_t)(unsigned)e0 * 64 + lane];
        float v0 = __uint_as_float((unsigned)(e0 >> 32));
        a0.x += v0 * bflo(u0); a0.y += v0 * bfhi(u0);
    }
    a0.x += a1.x + a2.x + a3.x;
    a0.y += a1.y + a2.y + a3.y;
    a0.x = a0.x > 0.f ? a0.x : 0.f;
    a0.y = a0.y > 0.f ? a0.y : 0.f;
    hb[(size_t)node * 64 + lane] = pack2(a0.x, a0.y);
}

// ---------------- GEMM2: pre2b[50000,32] = bf16(h @ W2) ----------------

__global__ __launch_bounds__(256) void gemm2_k(const unsigned* __restrict__ hb,
                                               const float* __restrict__ W2,
                                               unsigned short* __restrict__ pre2b) {
    __shared__ float hs[32][132];
    __shared__ float w2s[HIDDEN][N_CLASSES];
    const int t = threadIdx.x;
    const int row0 = blockIdx.x * 32;
#pragma unroll
    for (int j = 0; j < 4; ++j) {        // W2: 1024 float4
        int f = j * 256 + t;
        int r = f >> 3;
        int c = (f & 7) << 2;
        *(float4*)&w2s[r][c] = *(const float4*)(W2 + (size_t)r * N_CLASSES + c);
    }
#pragma unroll
    for (int j = 0; j < 2; ++j) {        // h tile: 32 rows x 64 uints = 2048 uints
        int f = j * 256 + t;
        int r = f >> 4;                  // 0..31
        int cu = (f & 15) << 2;          // uint col 0..60 step 4
        int grr = row0 + r;
        if (grr >= N_NODES) grr = N_NODES - 1;
        uint4 u = *(const uint4*)(hb + (size_t)grr * 64 + cu);
        hs[r][2 * cu + 0] = bflo(u.x); hs[r][2 * cu + 1] = bfhi(u.x);
        hs[r][2 * cu + 2] = bflo(u.y); hs[r][2 * cu + 3] = bfhi(u.y);
        hs[r][2 * cu + 4] = bflo(u.z); hs[r][2 * cu + 5] = bfhi(u.z);
        hs[r][2 * cu + 6] = bflo(u.w); hs[r][2 * cu + 7] = bfhi(u.w);
    }
    __syncthreads();
    const int r = t >> 3;
    const int c = (t & 7) << 2;
    float4 acc; acc.x = acc.y = acc.z = acc.w = 0.f;
#pragma unroll 16
    for (int kk = 0; kk < HIDDEN; ++kk) {
        float a = hs[r][kk];
        float4 b = *(const float4*)&w2s[kk][c];
        acc.x += a * b.x; acc.y += a * b.y; acc.z += a * b.z; acc.w += a * b.w;
    }
    int grr = row0 + r;
    if (grr < N_NODES) {
        uint2 o;
        o.x = pack2(acc.x, acc.y);
        o.y = pack2(acc.z, acc.w);
        *(uint2*)&pre2b[(size_t)grr * N_CLASSES + c] = o;
    }
}

// ---------------- SpMM2: out = A @ pre2 ; 16 lanes/edge, 2-deep unroll (8 edges in flight) ----------------

__global__ __launch_bounds__(256) void spmm2_k(const int* __restrict__ rp,
                                               const unsigned long long* __restrict__ ce,
                                               const unsigned* __restrict__ P2,
                                               float* __restrict__ out) {
    const int g = threadIdx.x >> 6;
    const int lane = threadIdx.x & 63;
    const int node = blockIdx.x * 4 + g;
    if (node >= N_NODES) return;
    const int s = rp[node], e = rp[node + 1];
    const int f2 = lane & 15;      // uint index: feats 2*f2, 2*f2+1
    const int par = lane >> 4;     // 0..3
    float ax0 = 0.f, ay0 = 0.f, ax1 = 0.f, ay1 = 0.f;
    int i = s + par;
    for (; i + 4 < e; i += 8) {
        unsigned long long e0 = ce[i], e1 = ce[i + 4];
        unsigned u0 = P2[(size_t)(unsigned)e0 * 16 + f2];
        unsigned u1 = P2[(size_t)(unsigned)e1 * 16 + f2];
        float v0 = __uint_as_float((unsigned)(e0 >> 32));
        float v1 = __uint_as_float((unsigned)(e1 >> 32));
        ax0 += v0 * bflo(u0); ay0 += v0 * bfhi(u0);
        ax1 += v1 * bflo(u1); ay1 += v1 * bfhi(u1);
    }
    if (i < e) {
        unsigned long long e0 = ce[i];
        unsigned u0 = P2[(size_t)(unsigned)e0 * 16 + f2];
        float v0 = __uint_as_float((unsigned)(e0 >> 32));
        ax0 += v0 * bflo(u0); ay0 += v0 * bfhi(u0);
    }
    float ax = ax0 + ax1, ay = ay0 + ay1;
    ax += __shfl_xor(ax, 16); ay += __shfl_xor(ay, 16);
    ax += __shfl_xor(ax, 32); ay += __shfl_xor(ay, 32);
    if (lane < 16) {
        float2 o; o.x = ax; o.y = ay;
        ((float2*)out)[(size_t)node * 16 + f2] = o;
    }
}

// ---------------- launch ----------------

extern "C" void kernel_launch(void* const* d_in, const int* in_sizes, int n_in,
                              void* d_out, int out_size, void* d_ws, size_t ws_size,
                              hipStream_t stream) {
    const float* x    = (const float*)d_in[0];
    const int* esrc   = (const int*)d_in[1];
    const int* edst   = (const int*)d_in[2];
    const float* ev   = (const float*)d_in[3];
    const float* W1   = (const float*)d_in[4];
    const float* W2   = (const float*)d_in[5];
    float* out        = (float*)d_out;

    // workspace layout; pre2b aliases pre1b (pre1b dead after spmm1)
    unsigned short* pre1b = (unsigned short*)d_ws;            // 6,400,000 ushort (12.8 MB)
    unsigned* hb          = (unsigned*)(pre1b + 6400000);     // 3,200,000 uint (12.8 MB)
    unsigned short* pre2b = pre1b;                            // alias
    unsigned long long* csr_ev = (unsigned long long*)(hb + 3200000);   // 800,000 u64 (6.4 MB)
    unsigned long long* tmp    = csr_ev + 800000;             // 196*6144 u64 (9.63 MB)
    int* row_ptr          = (int*)(tmp + (size_t)NBUCK * REG_STRIDE);   // 50,001 (pad 50,048)
    int* gcursor          = row_ptr + 50048;                  // 256
    unsigned short* W1t   = (unsigned short*)(gcursor + 256); // 65,536 ushort

    hipLaunchKernelGGL(w1conv_k,   dim3(256),  dim3(256), 0, stream, W1, W1t, gcursor);
    hipLaunchKernelGGL(bucket1_k,  dim3(391),  dim3(256), 0, stream, esrc, edst, ev, gcursor, tmp);
    hipLaunchKernelGGL(bucket2_k,  dim3(NBUCK),dim3(256), 0, stream, gcursor, tmp, csr_ev, row_ptr);

    hipLaunchKernelGGL(gemm1_mfma, dim3(256),  dim3(1024), 0, stream, x, W1t, pre1b);
    hipLaunchKernelGGL(spmm1_k,    dim3(12500),dim3(256), 0, stream, row_ptr, csr_ev, (const unsigned*)pre1b, hb);
    hipLaunchKernelGGL(gemm2_k,    dim3(1563), dim3(256), 0, stream, hb, W2, pre2b);
    hipLaunchKernelGGL(spmm2_k,    dim3(12500),dim3(256), 0, stream, row_ptr, csr_ev, (const unsigned*)pre2b, out);
}